// Round 23
// baseline (377.121 us; speedup 1.0000x reference)
//
#include <hip/hip_runtime.h>

typedef unsigned short u16;
typedef __attribute__((ext_vector_type(8))) short short8;
typedef __attribute__((ext_vector_type(4))) unsigned short u16x4;
typedef __attribute__((ext_vector_type(4))) float f32x4;

#define DEV __device__ __forceinline__
#define VMW(n) asm volatile("s_waitcnt vmcnt(" #n ")" ::: "memory")

DEV float bf2f(u16 u) { return __uint_as_float(((unsigned int)u) << 16); }
DEV u16 f2bf(float f) {
  unsigned int u = __float_as_uint(f);
  u += 0x7FFF + ((u >> 16) & 1);
  return (u16)(u >> 16);
}

// tanh-form GELU: 0.5x(1+tanh(a(x+bx^3))) = x - x*rcp(exp(2a(x+bx^3))+1)
DEV float fast_gelu(float x) {
  float z2 = 1.5957691216f * x * (1.0f + 0.044715f * x * x);  // 2*a*(x+b x^3)
  float e = __expf(z2);
  float r = __builtin_amdgcn_rcpf(e + 1.0f);
  return x - x * r;
}

DEV float redmax16(float v) {
  v = fmaxf(v, __shfl_xor(v, 1));
  v = fmaxf(v, __shfl_xor(v, 2));
  v = fmaxf(v, __shfl_xor(v, 4));
  v = fmaxf(v, __shfl_xor(v, 8));
  return v;
}
DEV float redsum16(float v) {
  v += __shfl_xor(v, 1);
  v += __shfl_xor(v, 2);
  v += __shfl_xor(v, 4);
  v += __shfl_xor(v, 8);
  return v;
}

// ------ fused transpose + cast f32 -> bf16 for all three weight matrices ----
__global__ __launch_bounds__(256) void transpose_all(const float* __restrict__ w_qkv,
                                                     const float* __restrict__ w_in,
                                                     const float* __restrict__ w_out,
                                                     u16* __restrict__ wqkvT,
                                                     u16* __restrict__ winT,
                                                     u16* __restrict__ woutT) {
  __shared__ u16 tile[32][33];
  int bid = blockIdx.x;
  const float* in;
  u16* out;
  int R, C, bx, by;
  if (bid < 3072) {
    in = w_qkv; out = wqkvT; R = 1024; C = 3072;
    bx = bid % 96; by = bid / 96;
  } else if (bid < 7168) {
    int b = bid - 3072;
    in = w_in; out = winT; R = 1024; C = 4096;
    bx = b % 128; by = b / 128;
  } else {
    int b = bid - 7168;
    in = w_out; out = woutT; R = 5120; C = 1024;
    bx = b % 32; by = b / 32;
  }
  int tx = threadIdx.x & 31, ty = threadIdx.x >> 5;  // 32 x 8
  int r0 = by * 32, c0 = bx * 32;
#pragma unroll
  for (int i = 0; i < 32; i += 8)
    tile[ty + i][tx] = f2bf(in[(size_t)(r0 + ty + i) * C + c0 + tx]);
  __syncthreads();
#pragma unroll
  for (int i = 0; i < 32; i += 8)
    out[(size_t)(c0 + ty + i) * R + r0 + tx] = tile[tx][ty + i];
}

// ---------------- RMSNorm: 8192 rows x 1024, f32 in -> bf16 out ----------------
__global__ __launch_bounds__(256) void rmsnorm_kernel(const float* __restrict__ x,
                                                      const float* __restrict__ w,
                                                      u16* __restrict__ xn) {
  int row = blockIdx.x, t = threadIdx.x;
  const float4* xr = reinterpret_cast<const float4*>(x + (size_t)row * 1024);
  float4 v = xr[t];
  float ss = v.x * v.x + v.y * v.y + v.z * v.z + v.w * v.w;
#pragma unroll
  for (int d = 1; d < 64; d <<= 1) ss += __shfl_xor(ss, d);
  __shared__ float red[4];
  if ((t & 63) == 0) red[t >> 6] = ss;
  __syncthreads();
  float tot = red[0] + red[1] + red[2] + red[3];
  float inv = rsqrtf(tot * (1.0f / 1024.0f) + 1e-6f);
  float4 wv = reinterpret_cast<const float4*>(w)[t];
  u16x4 o;
  o[0] = f2bf(v.x * inv * wv.x);
  o[1] = f2bf(v.y * inv * wv.y);
  o[2] = f2bf(v.z * inv * wv.z);
  o[3] = f2bf(v.w * inv * wv.w);
  *reinterpret_cast<u16x4*>(xn + (size_t)row * 1024 + t * 4) = o;
}

// ============ Pipelined GEMM (R22 exact, FROZEN): all three GEMMs ===========
// BM=256, BN=128, BK=64; 8 waves (4M x 2N). Triple-buffered LDS (144 KB),
// staging 1 tile ahead, counted vmcnt(6) at tile boundary, setprio, raw
// s_barrier, XOR-swizzled rows. Panel-pinned XCD remap (bid%8 == by%8).
// mode 1: bf16+GELU(tanh); 2: f32; 3: QKV fused epilogue.
DEV void stage_half(const u16* __restrict__ gbase, int K, int kt, char* dst, int w, int l) {
#pragma unroll
  for (int j = 0; j < 2; ++j) {
    int s = w * 2 + j;
    int row = s * 8 + (l >> 3);
    int ksrc = ((l & 7) ^ (l >> 3)) << 3;
    const u16* src = gbase + (size_t)row * K + kt + ksrc;
    __builtin_amdgcn_global_load_lds(
        (const __attribute__((address_space(1))) unsigned int*)src,
        (__attribute__((address_space(3))) unsigned int*)(dst + s * 1024 + l * 16),
        16, 0, 0);
  }
}

DEV short8 ldfrag(const char* base, int row, int slot) {
  return *reinterpret_cast<const short8*>(base + row * 128 + (((slot ^ (row & 7)) << 4)));
}

__global__ __launch_bounds__(512) void gemm256(const u16* __restrict__ A,
                                               const u16* __restrict__ BT,
                                               const float* __restrict__ bias,
                                               void* __restrict__ Cout,
                                               u16* __restrict__ vTout,
                                               const float* __restrict__ sp,
                                               const float* __restrict__ cp,
                                               int K, int ldc, int mode, int NBX) {
  __shared__ float4 lds_v[9216];  // 147456 B
  char* lds = (char*)lds_v;
  int t = threadIdx.x;
  int w = t >> 6, l = t & 63, c = l & 15, g = l >> 4;
  int wr = w >> 1, wc = w & 1;

  // panel-pinning remap: all NBX blocks of A-panel `by` share XCD by%8.
  int bid = blockIdx.x;
  int x8 = bid & 7, q = bid >> 3;
  int bx = q % NBX;
  int by = (q / NBX) * 8 + x8;

  size_t m0 = (size_t)by * 256, n0 = (size_t)bx * 128;
  const u16* Ab = A + m0 * K;
  const u16* Bb = BT + n0 * K;
  int KT = K >> 6;

  f32x4 zero4 = {0.f, 0.f, 0.f, 0.f};
  f32x4 acc[4][4];
#pragma unroll
  for (int a = 0; a < 4; ++a)
#pragma unroll
    for (int b2 = 0; b2 < 4; ++b2) acc[a][b2] = zero4;

#pragma unroll
  for (int pt = 0; pt < 2; ++pt) {
    int boff = pt * 49152;
    stage_half(Ab, K, pt * 64, lds + boff, w, l);
    stage_half(Ab + (size_t)128 * K, K, pt * 64, lds + boff + 16384, w, l);
    stage_half(Bb, K, pt * 64, lds + boff + 32768, w, l);
  }
  VMW(6);
  __builtin_amdgcn_s_barrier();

  for (int tt = 0; tt < KT; ++tt) {
    const char* Abuf = lds + (tt % 3) * 49152;
    const char* Bbuf = Abuf + 32768;
    int b2off = ((tt + 2) % 3) * 49152;
    int kt2 = (tt + 2) * 64;
    bool pf = (tt + 2 < KT);

    if (pf) {
      stage_half(Ab, K, kt2, lds + b2off, w, l);
      stage_half(Ab + (size_t)128 * K, K, kt2, lds + b2off + 16384, w, l);
    }
    {
      short8 bv[4], av[4];
#pragma unroll
      for (int nj = 0; nj < 4; ++nj) bv[nj] = ldfrag(Bbuf, wc * 64 + 16 * nj + c, g);
#pragma unroll
      for (int mi = 0; mi < 4; ++mi) av[mi] = ldfrag(Abuf, wr * 64 + 16 * mi + c, g);
      __builtin_amdgcn_s_setprio(1);
#pragma unroll
      for (int mi = 0; mi < 4; ++mi)
#pragma unroll
        for (int nj = 0; nj < 4; ++nj)
          acc[mi][nj] = __builtin_amdgcn_mfma_f32_16x16x32_bf16(av[mi], bv[nj], acc[mi][nj], 0, 0, 0);
      __builtin_amdgcn_s_setprio(0);
    }
    __builtin_amdgcn_s_barrier();

    if (pf) stage_half(Bb, K, kt2, lds + b2off + 32768, w, l);
    {
      short8 bv[4], av[4];
#pragma unroll
      for (int nj = 0; nj < 4; ++nj) bv[nj] = ldfrag(Bbuf, wc * 64 + 16 * nj + c, 4 + g);
#pragma unroll
      for (int mi = 0; mi < 4; ++mi) av[mi] = ldfrag(Abuf, wr * 64 + 16 * mi + c, 4 + g);
      __builtin_amdgcn_s_setprio(1);
#pragma unroll
      for (int mi = 0; mi < 4; ++mi)
#pragma unroll
        for (int nj = 0; nj < 4; ++nj)
          acc[mi][nj] = __builtin_amdgcn_mfma_f32_16x16x32_bf16(av[mi], bv[nj], acc[mi][nj], 0, 0, 0);
      __builtin_amdgcn_s_setprio(0);
    }
    if (tt + 1 < KT) {
      if (pf)
        VMW(6);
      else
        VMW(0);
      __builtin_amdgcn_s_barrier();
    }
  }

  // ---- epilogue ----
  if (mode == 3) {
    bool blockV = (n0 >= 2048);  // block-uniform: 2048 % 128 == 0
    if (!blockV) {
#pragma unroll
      for (int nj = 0; nj < 4; ++nj) {
        int col = (int)n0 + wc * 64 + 16 * nj + c;
        float bvv = bias[col];
        float sgn = (col & 1) ? 1.0f : -1.0f;
        float scq = (col < 1024) ? 0.125f : 1.0f;
        int d = col & 63;
#pragma unroll
        for (int mi = 0; mi < 4; ++mi) {
          size_t rbase = m0 + wr * 64 + 16 * mi + 4 * g;
#pragma unroll
          for (int r = 0; r < 4; ++r) {
            float fb = acc[mi][nj][r] + bvv;
            float fp = __shfl_xor(fb, 1);
            int pos = (int)((rbase + r) & 4095);
            float sv = sp[pos * 64 + d];
            float cv = cp[pos * 64 + d];
            ((u16*)Cout)[(rbase + r) * (size_t)ldc + col] = f2bf((fb * cv + sgn * fp * sv) * scq);
          }
        }
      }
    } else {
      int b16 = ((int)(m0 >> 12)) * 16;
#pragma unroll
      for (int nj = 0; nj < 4; ++nj) {
        int col = (int)n0 + wc * 64 + 16 * nj + c;
        float bvv = bias[col];
        int cv2 = col - 2048;
        int h = cv2 >> 6, d = cv2 & 63;
        u16* vb = vTout + ((size_t)(b16 + h)) * 262144 + (size_t)d * 4096;
#pragma unroll
        for (int mi = 0; mi < 4; ++mi) {
          size_t rbase = m0 + wr * 64 + 16 * mi + 4 * g;
          int s0 = (int)(rbase & 4095);
          u16x4 pk;
#pragma unroll
          for (int r = 0; r < 4; ++r) pk[r] = f2bf(acc[mi][nj][r] + bvv);
          *reinterpret_cast<u16x4*>(vb + s0) = pk;
        }
      }
    }
    return;
  }

#pragma unroll
  for (int nj = 0; nj < 4; ++nj) {
    int col = (int)n0 + wc * 64 + 16 * nj + c;
    float bvv = bias[col];
#pragma unroll
    for (int mi = 0; mi < 4; ++mi) {
      size_t rbase = m0 + wr * 64 + 16 * mi + 4 * g;
#pragma unroll
      for (int r = 0; r < 4; ++r) {
        float f = acc[mi][nj][r] + bvv;
        if (mode == 1) f = fast_gelu(f);
        size_t oidx = (rbase + r) * (size_t)ldc + col;
        if (mode == 2)
          ((float*)Cout)[oidx] = f;
        else
          ((u16*)Cout)[oidx] = f2bf(f);
      }
    }
  }
}

// ------- sliding-window causal attention (4-wave blocks, reg pipeline) ------
// 256 threads = 4 independent waves; wave w handles q-tile grp*4+w of one
// (b,h) -- waves share most of their K/V window (L2/L1 reuse), and 4x fewer
// blocks lifts resident waves/CU to the VGPR limit (8/CU). Per-wave code is
// the R22 kernel verbatim (T14 pipeline + T13 defer-max); no barriers.
__global__ __launch_bounds__(256) void attn_kernel(const u16* __restrict__ qk,
                                                   const u16* __restrict__ vT,
                                                   u16* __restrict__ comb) {
  int bid = blockIdx.x;          // 1024 blocks: (b,h,grp)
  int grp = bid & 31, h = (bid >> 5) & 15, b = bid >> 9;
  int wv = threadIdx.x >> 6;
  int qt = grp * 4 + wv;
  int l = threadIdx.x & 63, c = l & 15, g = l >> 4;
  int q0 = qt * 32;
  const u16* qb = qk + (size_t)b * 4096 * 2048 + h * 64;
  const u16* kb = qb + 1024;
  const u16* vt = vT + (size_t)(b * 16 + h) * 64 * 4096;
  __shared__ u16 Pl_all[4 * 32 * 72];
  u16* Pl = Pl_all + wv * 32 * 72;

  short8 qf[2][2];
#pragma unroll
  for (int mi = 0; mi < 2; ++mi)
#pragma unroll
    for (int kk = 0; kk < 2; ++kk)
      qf[mi][kk] = *reinterpret_cast<const short8*>(
          qb + (size_t)(q0 + 16 * mi + c) * 2048 + 32 * kk + 8 * g);

  f32x4 zero4 = {0.f, 0.f, 0.f, 0.f};
  f32x4 o[2][4];
  float mr[2][4], lr[2][4];
#pragma unroll
  for (int a = 0; a < 2; ++a)
#pragma unroll
    for (int d2 = 0; d2 < 4; ++d2) {
      o[a][d2] = zero4;
      mr[a][d2] = -1e30f;
      lr[a][d2] = 0.f;
    }

  int t_lo = (q0 >= 480) ? ((q0 - 480) >> 6) : 0;
  int t_hi = (q0 + 31) >> 6;

  short8 kfc[2][4], kfn[2][4], bv[2][4];
#pragma unroll
  for (int kk = 0; kk < 2; ++kk)
#pragma unroll
    for (int nj = 0; nj < 4; ++nj)
      kfc[kk][nj] = *reinterpret_cast<const short8*>(
          kb + (size_t)(t_lo * 64 + 16 * nj + c) * 2048 + 32 * kk + 8 * g);

  for (int tt = t_lo; tt <= t_hi; ++tt) {
    int kt0 = tt * 64;

    // issue V[t] loads (consumed at PV, after softmax)
#pragma unroll
    for (int kk = 0; kk < 2; ++kk)
#pragma unroll
      for (int dj = 0; dj < 4; ++dj)
        bv[kk][dj] = *reinterpret_cast<const short8*>(
            vt + (size_t)(16 * dj + c) * 4096 + kt0 + 32 * kk + 8 * g);

    // issue K[t+1] loads (consumed at the rotate, after PV)
    if (tt < t_hi) {
#pragma unroll
      for (int kk = 0; kk < 2; ++kk)
#pragma unroll
        for (int nj = 0; nj < 4; ++nj)
          kfn[kk][nj] = *reinterpret_cast<const short8*>(
              kb + (size_t)(kt0 + 64 + 16 * nj + c) * 2048 + 32 * kk + 8 * g);
    }

    // QK^T with current (pre-loaded) K frags
    f32x4 s[2][4];
#pragma unroll
    for (int a = 0; a < 2; ++a)
#pragma unroll
      for (int d2 = 0; d2 < 4; ++d2) s[a][d2] = zero4;
#pragma unroll
    for (int kk = 0; kk < 2; ++kk)
#pragma unroll
      for (int mi = 0; mi < 2; ++mi)
#pragma unroll
        for (int nj = 0; nj < 4; ++nj)
          s[mi][nj] = __builtin_amdgcn_mfma_f32_16x16x32_bf16(qf[mi][kk], kfc[kk][nj], s[mi][nj], 0, 0, 0);

    // mask only on the boundary tiles (wave-uniform branch)
    bool mc = (tt == t_hi), mw = (tt == t_lo);
    if (mc | mw) {
#pragma unroll
      for (int mi = 0; mi < 2; ++mi)
#pragma unroll
        for (int nj = 0; nj < 4; ++nj)
#pragma unroll
          for (int r = 0; r < 4; ++r) {
            int qg = q0 + 16 * mi + 4 * g + r;
            int kg = kt0 + 16 * nj + c;
            if ((mc && kg > qg) || (mw && qg - kg >= 512)) s[mi][nj][r] = -1e30f;
          }
    }

    // tile maxima + defer-max decision (wave-uniform)
    float tmv[2][4];
    float dmax = -1e30f;
#pragma unroll
    for (int mi = 0; mi < 2; ++mi)
#pragma unroll
      for (int r = 0; r < 4; ++r) {
        float tm = fmaxf(fmaxf(s[mi][0][r], s[mi][1][r]), fmaxf(s[mi][2][r], s[mi][3][r]));
        tm = redmax16(tm);
        tmv[mi][r] = tm;
        dmax = fmaxf(dmax, tm - mr[mi][r]);
      }
    if (!__all(dmax <= 8.0f)) {
#pragma unroll
      for (int mi = 0; mi < 2; ++mi)
#pragma unroll
        for (int r = 0; r < 4; ++r) {
          float mn = fmaxf(mr[mi][r], tmv[mi][r]);
          float a = __expf(mr[mi][r] - mn);
          mr[mi][r] = mn;
          lr[mi][r] *= a;
#pragma unroll
          for (int dj = 0; dj < 4; ++dj) o[mi][dj][r] *= a;
        }
    }

#pragma unroll
    for (int mi = 0; mi < 2; ++mi)
#pragma unroll
      for (int r = 0; r < 4; ++r) {
        float rs = 0.f;
        u16* pp = &Pl[(16 * mi + 4 * g + r) * 72 + c];
#pragma unroll
        for (int nj = 0; nj < 4; ++nj) {
          float p = __expf(s[mi][nj][r] - mr[mi][r]);
          rs += p;
          pp[16 * nj] = f2bf(p);  // natural k order, imm-offset ds_write_b16
        }
        rs = redsum16(rs);
        lr[mi][r] += rs;
      }

    // PV: A-frag from Pl, B-frag = V regs issued before softmax
#pragma unroll
    for (int kk = 0; kk < 2; ++kk) {
      short8 pa[2];
#pragma unroll
      for (int mi = 0; mi < 2; ++mi)
        pa[mi] = *reinterpret_cast<const short8*>(&Pl[(16 * mi + c) * 72 + 32 * kk + 8 * g]);
#pragma unroll
      for (int mi = 0; mi < 2; ++mi)
#pragma unroll
        for (int dj = 0; dj < 4; ++dj)
          o[mi][dj] = __builtin_amdgcn_mfma_f32_16x16x32_bf16(pa[mi], bv[kk][dj], o[mi][dj], 0, 0, 0);
    }

    // rotate: consume K[t+1] loads (they were in flight the whole tile)
    if (tt < t_hi) {
#pragma unroll
      for (int kk = 0; kk < 2; ++kk)
#pragma unroll
        for (int nj = 0; nj < 4; ++nj) kfc[kk][nj] = kfn[kk][nj];
    }
  }

  u16* ob = comb + (size_t)(b * 4096 + q0) * 5120 + h * 64;
#pragma unroll
  for (int mi = 0; mi < 2; ++mi)
#pragma unroll
    for (int r = 0; r < 4; ++r) {
      float inv = __builtin_amdgcn_rcpf(lr[mi][r]);
#pragma unroll
      for (int dj = 0; dj < 4; ++dj)
        ob[(size_t)(16 * mi + 4 * g + r) * 5120 + 16 * dj + c] = f2bf(o[mi][dj][r] * inv);
    }
}

// ---------------- launch ----------------
extern "C" void kernel_launch(void* const* d_in, const int* in_sizes, int n_in,
                              void* d_out, int out_size, void* d_ws, size_t ws_size,
                              hipStream_t stream) {
  const float* x = (const float*)d_in[0];
  const float* sinp = (const float*)d_in[1];
  const float* cosp = (const float*)d_in[2];
  const float* norm_w = (const float*)d_in[3];
  const float* w_qkv = (const float*)d_in[4];
  const float* b_qkv = (const float*)d_in[5];
  const float* w_in = (const float*)d_in[6];
  const float* b_in = (const float*)d_in[7];
  const float* w_out = (const float*)d_in[8];
  const float* b_out = (const float*)d_in[9];
  float* out = (float*)d_out;

  char* ws = (char*)d_ws;
  u16* xn = (u16*)(ws);                        // 8192*1024*2      = 16,777,216
  u16* qk = (u16*)(ws + 16777216);             // 8192*2048*2      = 33,554,432
  u16* vT = (u16*)(ws + 50331648);             // 32*64*4096*2     = 16,777,216
  u16* comb = (u16*)(ws + 67108864);           // 8192*5120*2      = 83,886,080
  u16* wqkvT = (u16*)(ws + 150994944);         // 3072*1024*2      = 6,291,456
  u16* winT = (u16*)(ws + 157286400);          // 4096*1024*2      = 8,388,608
  u16* woutT = (u16*)(ws + 165675008);         // 1024*5120*2      = 10,485,760

  transpose_all<<<12288, 256, 0, stream>>>(w_qkv, w_in, w_out, wqkvT, winT, woutT);

  rmsnorm_kernel<<<8192, 256, 0, stream>>>(x, norm_w, xn);

  // qkv GEMM, fused epilogue: q/k -> rope+scale -> qk[2048]; V -> vT directly
  gemm256<<<768, 512, 0, stream>>>(
      xn, wqkvT, b_qkv, qk, vT, sinp, cosp, 1024, 2048, 3, 24);

  // ff = gelu(xn @ w_in + b_in) -> comb cols [1024, 5120)  (last use of xn)
  gemm256<<<1024, 512, 0, stream>>>(
      xn, winT, b_in, comb + 1024, nullptr, nullptr, nullptr, 1024, 5120, 1, 32);

  attn_kernel<<<1024, 256, 0, stream>>>(qk, vT, comb);

  // out = comb @ w_out + b_out  (f32 out)
  gemm256<<<256, 512, 0, stream>>>(
      comb, woutT, b_out, out, nullptr, nullptr, nullptr, 5120, 1024, 2, 8);
}

// Round 24
// 344.687 us; speedup vs baseline: 1.0941x; 1.0941x over previous
//
#include <hip/hip_runtime.h>

typedef unsigned short u16;
typedef __attribute__((ext_vector_type(8))) short short8;
typedef __attribute__((ext_vector_type(4))) unsigned short u16x4;
typedef __attribute__((ext_vector_type(4))) float f32x4;

#define DEV __device__ __forceinline__
#define VMW(n) asm volatile("s_waitcnt vmcnt(" #n ")" ::: "memory")

DEV float bf2f(u16 u) { return __uint_as_float(((unsigned int)u) << 16); }
DEV u16 f2bf(float f) {
  unsigned int u = __float_as_uint(f);
  u += 0x7FFF + ((u >> 16) & 1);
  return (u16)(u >> 16);
}

// tanh-form GELU: 0.5x(1+tanh(a(x+bx^3))) = x - x*rcp(exp(2a(x+bx^3))+1)
DEV float fast_gelu(float x) {
  float z2 = 1.5957691216f * x * (1.0f + 0.044715f * x * x);  // 2*a*(x+b x^3)
  float e = __expf(z2);
  float r = __builtin_amdgcn_rcpf(e + 1.0f);
  return x - x * r;
}

DEV float redmax16(float v) {
  v = fmaxf(v, __shfl_xor(v, 1));
  v = fmaxf(v, __shfl_xor(v, 2));
  v = fmaxf(v, __shfl_xor(v, 4));
  v = fmaxf(v, __shfl_xor(v, 8));
  return v;
}
DEV float redsum16(float v) {
  v += __shfl_xor(v, 1);
  v += __shfl_xor(v, 2);
  v += __shfl_xor(v, 4);
  v += __shfl_xor(v, 8);
  return v;
}

// ------ fused transpose + cast f32 -> bf16 for all three weight matrices ----
__global__ __launch_bounds__(256) void transpose_all(const float* __restrict__ w_qkv,
                                                     const float* __restrict__ w_in,
                                                     const float* __restrict__ w_out,
                                                     u16* __restrict__ wqkvT,
                                                     u16* __restrict__ winT,
                                                     u16* __restrict__ woutT) {
  __shared__ u16 tile[32][33];
  int bid = blockIdx.x;
  const float* in;
  u16* out;
  int R, C, bx, by;
  if (bid < 3072) {
    in = w_qkv; out = wqkvT; R = 1024; C = 3072;
    bx = bid % 96; by = bid / 96;
  } else if (bid < 7168) {
    int b = bid - 3072;
    in = w_in; out = winT; R = 1024; C = 4096;
    bx = b % 128; by = b / 128;
  } else {
    int b = bid - 7168;
    in = w_out; out = woutT; R = 5120; C = 1024;
    bx = b % 32; by = b / 32;
  }
  int tx = threadIdx.x & 31, ty = threadIdx.x >> 5;  // 32 x 8
  int r0 = by * 32, c0 = bx * 32;
#pragma unroll
  for (int i = 0; i < 32; i += 8)
    tile[ty + i][tx] = f2bf(in[(size_t)(r0 + ty + i) * C + c0 + tx]);
  __syncthreads();
#pragma unroll
  for (int i = 0; i < 32; i += 8)
    out[(size_t)(c0 + ty + i) * R + r0 + tx] = tile[tx][ty + i];
}

// ---------------- RMSNorm: 8192 rows x 1024, f32 in -> bf16 out ----------------
__global__ __launch_bounds__(256) void rmsnorm_kernel(const float* __restrict__ x,
                                                      const float* __restrict__ w,
                                                      u16* __restrict__ xn) {
  int row = blockIdx.x, t = threadIdx.x;
  const float4* xr = reinterpret_cast<const float4*>(x + (size_t)row * 1024);
  float4 v = xr[t];
  float ss = v.x * v.x + v.y * v.y + v.z * v.z + v.w * v.w;
#pragma unroll
  for (int d = 1; d < 64; d <<= 1) ss += __shfl_xor(ss, d);
  __shared__ float red[4];
  if ((t & 63) == 0) red[t >> 6] = ss;
  __syncthreads();
  float tot = red[0] + red[1] + red[2] + red[3];
  float inv = rsqrtf(tot * (1.0f / 1024.0f) + 1e-6f);
  float4 wv = reinterpret_cast<const float4*>(w)[t];
  u16x4 o;
  o[0] = f2bf(v.x * inv * wv.x);
  o[1] = f2bf(v.y * inv * wv.y);
  o[2] = f2bf(v.z * inv * wv.z);
  o[3] = f2bf(v.w * inv * wv.w);
  *reinterpret_cast<u16x4*>(xn + (size_t)row * 1024 + t * 4) = o;
}

// ============ Pipelined GEMM (R22 exact, FROZEN): all three GEMMs ===========
// BM=256, BN=128, BK=64; 8 waves (4M x 2N). Triple-buffered LDS (144 KB),
// staging 1 tile ahead, counted vmcnt(6) at tile boundary, setprio, raw
// s_barrier, XOR-swizzled rows. Panel-pinned XCD remap (bid%8 == by%8).
// mode 1: bf16+GELU(tanh); 2: f32; 3: QKV fused epilogue.
DEV void stage_half(const u16* __restrict__ gbase, int K, int kt, char* dst, int w, int l) {
#pragma unroll
  for (int j = 0; j < 2; ++j) {
    int s = w * 2 + j;
    int row = s * 8 + (l >> 3);
    int ksrc = ((l & 7) ^ (l >> 3)) << 3;
    const u16* src = gbase + (size_t)row * K + kt + ksrc;
    __builtin_amdgcn_global_load_lds(
        (const __attribute__((address_space(1))) unsigned int*)src,
        (__attribute__((address_space(3))) unsigned int*)(dst + s * 1024 + l * 16),
        16, 0, 0);
  }
}

DEV short8 ldfrag(const char* base, int row, int slot) {
  return *reinterpret_cast<const short8*>(base + row * 128 + (((slot ^ (row & 7)) << 4)));
}

__global__ __launch_bounds__(512) void gemm256(const u16* __restrict__ A,
                                               const u16* __restrict__ BT,
                                               const float* __restrict__ bias,
                                               void* __restrict__ Cout,
                                               u16* __restrict__ vTout,
                                               const float* __restrict__ sp,
                                               const float* __restrict__ cp,
                                               int K, int ldc, int mode, int NBX) {
  __shared__ float4 lds_v[9216];  // 147456 B
  char* lds = (char*)lds_v;
  int t = threadIdx.x;
  int w = t >> 6, l = t & 63, c = l & 15, g = l >> 4;
  int wr = w >> 1, wc = w & 1;

  // panel-pinning remap: all NBX blocks of A-panel `by` share XCD by%8.
  int bid = blockIdx.x;
  int x8 = bid & 7, q = bid >> 3;
  int bx = q % NBX;
  int by = (q / NBX) * 8 + x8;

  size_t m0 = (size_t)by * 256, n0 = (size_t)bx * 128;
  const u16* Ab = A + m0 * K;
  const u16* Bb = BT + n0 * K;
  int KT = K >> 6;

  f32x4 zero4 = {0.f, 0.f, 0.f, 0.f};
  f32x4 acc[4][4];
#pragma unroll
  for (int a = 0; a < 4; ++a)
#pragma unroll
    for (int b2 = 0; b2 < 4; ++b2) acc[a][b2] = zero4;

#pragma unroll
  for (int pt = 0; pt < 2; ++pt) {
    int boff = pt * 49152;
    stage_half(Ab, K, pt * 64, lds + boff, w, l);
    stage_half(Ab + (size_t)128 * K, K, pt * 64, lds + boff + 16384, w, l);
    stage_half(Bb, K, pt * 64, lds + boff + 32768, w, l);
  }
  VMW(6);
  __builtin_amdgcn_s_barrier();

  for (int tt = 0; tt < KT; ++tt) {
    const char* Abuf = lds + (tt % 3) * 49152;
    const char* Bbuf = Abuf + 32768;
    int b2off = ((tt + 2) % 3) * 49152;
    int kt2 = (tt + 2) * 64;
    bool pf = (tt + 2 < KT);

    if (pf) {
      stage_half(Ab, K, kt2, lds + b2off, w, l);
      stage_half(Ab + (size_t)128 * K, K, kt2, lds + b2off + 16384, w, l);
    }
    {
      short8 bv[4], av[4];
#pragma unroll
      for (int nj = 0; nj < 4; ++nj) bv[nj] = ldfrag(Bbuf, wc * 64 + 16 * nj + c, g);
#pragma unroll
      for (int mi = 0; mi < 4; ++mi) av[mi] = ldfrag(Abuf, wr * 64 + 16 * mi + c, g);
      __builtin_amdgcn_s_setprio(1);
#pragma unroll
      for (int mi = 0; mi < 4; ++mi)
#pragma unroll
        for (int nj = 0; nj < 4; ++nj)
          acc[mi][nj] = __builtin_amdgcn_mfma_f32_16x16x32_bf16(av[mi], bv[nj], acc[mi][nj], 0, 0, 0);
      __builtin_amdgcn_s_setprio(0);
    }
    __builtin_amdgcn_s_barrier();

    if (pf) stage_half(Bb, K, kt2, lds + b2off + 32768, w, l);
    {
      short8 bv[4], av[4];
#pragma unroll
      for (int nj = 0; nj < 4; ++nj) bv[nj] = ldfrag(Bbuf, wc * 64 + 16 * nj + c, 4 + g);
#pragma unroll
      for (int mi = 0; mi < 4; ++mi) av[mi] = ldfrag(Abuf, wr * 64 + 16 * mi + c, 4 + g);
      __builtin_amdgcn_s_setprio(1);
#pragma unroll
      for (int mi = 0; mi < 4; ++mi)
#pragma unroll
        for (int nj = 0; nj < 4; ++nj)
          acc[mi][nj] = __builtin_amdgcn_mfma_f32_16x16x32_bf16(av[mi], bv[nj], acc[mi][nj], 0, 0, 0);
      __builtin_amdgcn_s_setprio(0);
    }
    if (tt + 1 < KT) {
      if (pf)
        VMW(6);
      else
        VMW(0);
      __builtin_amdgcn_s_barrier();
    }
  }

  // ---- epilogue ----
  if (mode == 3) {
    bool blockV = (n0 >= 2048);  // block-uniform: 2048 % 128 == 0
    if (!blockV) {
#pragma unroll
      for (int nj = 0; nj < 4; ++nj) {
        int col = (int)n0 + wc * 64 + 16 * nj + c;
        float bvv = bias[col];
        float sgn = (col & 1) ? 1.0f : -1.0f;
        float scq = (col < 1024) ? 0.125f : 1.0f;
        int d = col & 63;
#pragma unroll
        for (int mi = 0; mi < 4; ++mi) {
          size_t rbase = m0 + wr * 64 + 16 * mi + 4 * g;
#pragma unroll
          for (int r = 0; r < 4; ++r) {
            float fb = acc[mi][nj][r] + bvv;
            float fp = __shfl_xor(fb, 1);
            int pos = (int)((rbase + r) & 4095);
            float sv = sp[pos * 64 + d];
            float cv = cp[pos * 64 + d];
            ((u16*)Cout)[(rbase + r) * (size_t)ldc + col] = f2bf((fb * cv + sgn * fp * sv) * scq);
          }
        }
      }
    } else {
      int b16 = ((int)(m0 >> 12)) * 16;
#pragma unroll
      for (int nj = 0; nj < 4; ++nj) {
        int col = (int)n0 + wc * 64 + 16 * nj + c;
        float bvv = bias[col];
        int cv2 = col - 2048;
        int h = cv2 >> 6, d = cv2 & 63;
        u16* vb = vTout + ((size_t)(b16 + h)) * 262144 + (size_t)d * 4096;
#pragma unroll
        for (int mi = 0; mi < 4; ++mi) {
          size_t rbase = m0 + wr * 64 + 16 * mi + 4 * g;
          int s0 = (int)(rbase & 4095);
          u16x4 pk;
#pragma unroll
          for (int r = 0; r < 4; ++r) pk[r] = f2bf(acc[mi][nj][r] + bvv);
          *reinterpret_cast<u16x4*>(vb + s0) = pk;
        }
      }
    }
    return;
  }

#pragma unroll
  for (int nj = 0; nj < 4; ++nj) {
    int col = (int)n0 + wc * 64 + 16 * nj + c;
    float bvv = bias[col];
#pragma unroll
    for (int mi = 0; mi < 4; ++mi) {
      size_t rbase = m0 + wr * 64 + 16 * mi + 4 * g;
#pragma unroll
      for (int r = 0; r < 4; ++r) {
        float f = acc[mi][nj][r] + bvv;
        if (mode == 1) f = fast_gelu(f);
        size_t oidx = (rbase + r) * (size_t)ldc + col;
        if (mode == 2)
          ((float*)Cout)[oidx] = f;
        else
          ((u16*)Cout)[oidx] = f2bf(f);
      }
    }
  }
}

// ------------- sliding-window causal attention (R22 exact) ------------------
// 1 wave per 32-query tile, no barriers. grid = 4096, block = 64.
// qk rows: [q(1024)|k(1024)], stride 2048, pre-roped, q pre-scaled 0.125.
// K[t+1] and V[t] issued early, consumed late (T14). Defer-max (T13).
// (R23 lesson: 4-wave packing shrank the register budget -> compiler sank
// the pipeline loads; keep 1-wave blocks, no VGPR cap.)
__global__ __launch_bounds__(64) void attn_kernel(const u16* __restrict__ qk,
                                                  const u16* __restrict__ vT,
                                                  u16* __restrict__ comb) {
  int bid = blockIdx.x;
  int swz = ((bid & 7) << 9) + (bid >> 3);  // 4096/8 = 512 per XCD
  int qt = swz & 127, h = (swz >> 7) & 15, b = swz >> 11;
  int l = threadIdx.x, c = l & 15, g = l >> 4;
  int q0 = qt * 32;
  const u16* qb = qk + (size_t)b * 4096 * 2048 + h * 64;
  const u16* kb = qb + 1024;
  const u16* vt = vT + (size_t)(b * 16 + h) * 64 * 4096;
  __shared__ u16 Pl[32 * 72];

  short8 qf[2][2];
#pragma unroll
  for (int mi = 0; mi < 2; ++mi)
#pragma unroll
    for (int kk = 0; kk < 2; ++kk)
      qf[mi][kk] = *reinterpret_cast<const short8*>(
          qb + (size_t)(q0 + 16 * mi + c) * 2048 + 32 * kk + 8 * g);

  f32x4 zero4 = {0.f, 0.f, 0.f, 0.f};
  f32x4 o[2][4];
  float mr[2][4], lr[2][4];
#pragma unroll
  for (int a = 0; a < 2; ++a)
#pragma unroll
    for (int d2 = 0; d2 < 4; ++d2) {
      o[a][d2] = zero4;
      mr[a][d2] = -1e30f;
      lr[a][d2] = 0.f;
    }

  int t_lo = (q0 >= 480) ? ((q0 - 480) >> 6) : 0;
  int t_hi = (q0 + 31) >> 6;

  short8 kfc[2][4], kfn[2][4], bv[2][4];
#pragma unroll
  for (int kk = 0; kk < 2; ++kk)
#pragma unroll
    for (int nj = 0; nj < 4; ++nj)
      kfc[kk][nj] = *reinterpret_cast<const short8*>(
          kb + (size_t)(t_lo * 64 + 16 * nj + c) * 2048 + 32 * kk + 8 * g);

  for (int tt = t_lo; tt <= t_hi; ++tt) {
    int kt0 = tt * 64;

    // issue V[t] loads (consumed at PV, after softmax)
#pragma unroll
    for (int kk = 0; kk < 2; ++kk)
#pragma unroll
      for (int dj = 0; dj < 4; ++dj)
        bv[kk][dj] = *reinterpret_cast<const short8*>(
            vt + (size_t)(16 * dj + c) * 4096 + kt0 + 32 * kk + 8 * g);

    // issue K[t+1] loads (consumed at the rotate, after PV)
    if (tt < t_hi) {
#pragma unroll
      for (int kk = 0; kk < 2; ++kk)
#pragma unroll
        for (int nj = 0; nj < 4; ++nj)
          kfn[kk][nj] = *reinterpret_cast<const short8*>(
              kb + (size_t)(kt0 + 64 + 16 * nj + c) * 2048 + 32 * kk + 8 * g);
    }

    // QK^T with current (pre-loaded) K frags
    f32x4 s[2][4];
#pragma unroll
    for (int a = 0; a < 2; ++a)
#pragma unroll
      for (int d2 = 0; d2 < 4; ++d2) s[a][d2] = zero4;
#pragma unroll
    for (int kk = 0; kk < 2; ++kk)
#pragma unroll
      for (int mi = 0; mi < 2; ++mi)
#pragma unroll
        for (int nj = 0; nj < 4; ++nj)
          s[mi][nj] = __builtin_amdgcn_mfma_f32_16x16x32_bf16(qf[mi][kk], kfc[kk][nj], s[mi][nj], 0, 0, 0);

    // mask only on the boundary tiles (wave-uniform branch)
    bool mc = (tt == t_hi), mw = (tt == t_lo);
    if (mc | mw) {
#pragma unroll
      for (int mi = 0; mi < 2; ++mi)
#pragma unroll
        for (int nj = 0; nj < 4; ++nj)
#pragma unroll
          for (int r = 0; r < 4; ++r) {
            int qg = q0 + 16 * mi + 4 * g + r;
            int kg = kt0 + 16 * nj + c;
            if ((mc && kg > qg) || (mw && qg - kg >= 512)) s[mi][nj][r] = -1e30f;
          }
    }

    // tile maxima + defer-max decision (wave-uniform)
    float tmv[2][4];
    float dmax = -1e30f;
#pragma unroll
    for (int mi = 0; mi < 2; ++mi)
#pragma unroll
      for (int r = 0; r < 4; ++r) {
        float tm = fmaxf(fmaxf(s[mi][0][r], s[mi][1][r]), fmaxf(s[mi][2][r], s[mi][3][r]));
        tm = redmax16(tm);
        tmv[mi][r] = tm;
        dmax = fmaxf(dmax, tm - mr[mi][r]);
      }
    if (!__all(dmax <= 8.0f)) {
#pragma unroll
      for (int mi = 0; mi < 2; ++mi)
#pragma unroll
        for (int r = 0; r < 4; ++r) {
          float mn = fmaxf(mr[mi][r], tmv[mi][r]);
          float a = __expf(mr[mi][r] - mn);
          mr[mi][r] = mn;
          lr[mi][r] *= a;
#pragma unroll
          for (int dj = 0; dj < 4; ++dj) o[mi][dj][r] *= a;
        }
    }

#pragma unroll
    for (int mi = 0; mi < 2; ++mi)
#pragma unroll
      for (int r = 0; r < 4; ++r) {
        float rs = 0.f;
        u16* pp = &Pl[(16 * mi + 4 * g + r) * 72 + c];
#pragma unroll
        for (int nj = 0; nj < 4; ++nj) {
          float p = __expf(s[mi][nj][r] - mr[mi][r]);
          rs += p;
          pp[16 * nj] = f2bf(p);  // natural k order, imm-offset ds_write_b16
        }
        rs = redsum16(rs);
        lr[mi][r] += rs;
      }

    // PV: A-frag from Pl, B-frag = V regs issued before softmax
#pragma unroll
    for (int kk = 0; kk < 2; ++kk) {
      short8 pa[2];
#pragma unroll
      for (int mi = 0; mi < 2; ++mi)
        pa[mi] = *reinterpret_cast<const short8*>(&Pl[(16 * mi + c) * 72 + 32 * kk + 8 * g]);
#pragma unroll
      for (int mi = 0; mi < 2; ++mi)
#pragma unroll
        for (int dj = 0; dj < 4; ++dj)
          o[mi][dj] = __builtin_amdgcn_mfma_f32_16x16x32_bf16(pa[mi], bv[kk][dj], o[mi][dj], 0, 0, 0);
    }

    // rotate: consume K[t+1] loads (they were in flight the whole tile)
    if (tt < t_hi) {
#pragma unroll
      for (int kk = 0; kk < 2; ++kk)
#pragma unroll
        for (int nj = 0; nj < 4; ++nj) kfc[kk][nj] = kfn[kk][nj];
    }
  }

  u16* ob = comb + (size_t)(b * 4096 + q0) * 5120 + h * 64;
#pragma unroll
  for (int mi = 0; mi < 2; ++mi)
#pragma unroll
    for (int r = 0; r < 4; ++r) {
      float inv = __builtin_amdgcn_rcpf(lr[mi][r]);
#pragma unroll
      for (int dj = 0; dj < 4; ++dj)
        ob[(size_t)(16 * mi + 4 * g + r) * 5120 + 16 * dj + c] = f2bf(o[mi][dj][r] * inv);
    }
}

// ---------------- launch ----------------
extern "C" void kernel_launch(void* const* d_in, const int* in_sizes, int n_in,
                              void* d_out, int out_size, void* d_ws, size_t ws_size,
                              hipStream_t stream) {
  const float* x = (const float*)d_in[0];
  const float* sinp = (const float*)d_in[1];
  const float* cosp = (const float*)d_in[2];
  const float* norm_w = (const float*)d_in[3];
  const float* w_qkv = (const float*)d_in[4];
  const float* b_qkv = (const float*)d_in[5];
  const float* w_in = (const float*)d_in[6];
  const float* b_in = (const float*)d_in[7];
  const float* w_out = (const float*)d_in[8];
  const float* b_out = (const float*)d_in[9];
  float* out = (float*)d_out;

  char* ws = (char*)d_ws;
  u16* xn = (u16*)(ws);                        // 8192*1024*2      = 16,777,216
  u16* qk = (u16*)(ws + 16777216);             // 8192*2048*2      = 33,554,432
  u16* vT = (u16*)(ws + 50331648);             // 32*64*4096*2     = 16,777,216
  u16* comb = (u16*)(ws + 67108864);           // 8192*5120*2      = 83,886,080
  u16* wqkvT = (u16*)(ws + 150994944);         // 3072*1024*2      = 6,291,456
  u16* winT = (u16*)(ws + 157286400);          // 4096*1024*2      = 8,388,608
  u16* woutT = (u16*)(ws + 165675008);         // 1024*5120*2      = 10,485,760

  transpose_all<<<12288, 256, 0, stream>>>(w_qkv, w_in, w_out, wqkvT, winT, woutT);

  rmsnorm_kernel<<<8192, 256, 0, stream>>>(x, norm_w, xn);

  // qkv GEMM, fused epilogue: q/k -> rope+scale -> qk[2048]; V -> vT directly
  gemm256<<<768, 512, 0, stream>>>(
      xn, wqkvT, b_qkv, qk, vT, sinp, cosp, 1024, 2048, 3, 24);

  // ff = gelu(xn @ w_in + b_in) -> comb cols [1024, 5120)  (last use of xn)
  gemm256<<<1024, 512, 0, stream>>>(
      xn, winT, b_in, comb + 1024, nullptr, nullptr, nullptr, 1024, 5120, 1, 32);

  attn_kernel<<<4096, 64, 0, stream>>>(qk, vT, comb);

  // out = comb @ w_out + b_out  (f32 out)
  gemm256<<<256, 512, 0, stream>>>(
      comb, woutT, b_out, out, nullptr, nullptr, nullptr, 5120, 1024, 2, 8);
}

// Round 26
// 336.691 us; speedup vs baseline: 1.1201x; 1.0237x over previous
//
#include <hip/hip_runtime.h>

typedef unsigned short u16;
typedef __attribute__((ext_vector_type(8))) short short8;
typedef __attribute__((ext_vector_type(4))) unsigned short u16x4;
typedef __attribute__((ext_vector_type(4))) float f32x4;

#define DEV __device__ __forceinline__
#define VMW(n) asm volatile("s_waitcnt vmcnt(" #n ")" ::: "memory")

DEV float bf2f(u16 u) { return __uint_as_float(((unsigned int)u) << 16); }
DEV u16 f2bf(float f) {
  unsigned int u = __float_as_uint(f);
  u += 0x7FFF + ((u >> 16) & 1);
  return (u16)(u >> 16);
}

// tanh-form GELU: 0.5x(1+tanh(a(x+bx^3))) = x - x*rcp(exp(2a(x+bx^3))+1)
DEV float fast_gelu(float x) {
  float z2 = 1.5957691216f * x * (1.0f + 0.044715f * x * x);  // 2*a*(x+b x^3)
  float e = __expf(z2);
  float r = __builtin_amdgcn_rcpf(e + 1.0f);
  return x - x * r;
}

DEV float redmax16(float v) {
  v = fmaxf(v, __shfl_xor(v, 1));
  v = fmaxf(v, __shfl_xor(v, 2));
  v = fmaxf(v, __shfl_xor(v, 4));
  v = fmaxf(v, __shfl_xor(v, 8));
  return v;
}
DEV float redsum16(float v) {
  v += __shfl_xor(v, 1);
  v += __shfl_xor(v, 2);
  v += __shfl_xor(v, 4);
  v += __shfl_xor(v, 8);
  return v;
}

// ------ fused transpose + cast f32 -> bf16 for all three weight matrices ----
__global__ __launch_bounds__(256) void transpose_all(const float* __restrict__ w_qkv,
                                                     const float* __restrict__ w_in,
                                                     const float* __restrict__ w_out,
                                                     u16* __restrict__ wqkvT,
                                                     u16* __restrict__ winT,
                                                     u16* __restrict__ woutT) {
  __shared__ u16 tile[32][33];
  int bid = blockIdx.x;
  const float* in;
  u16* out;
  int R, C, bx, by;
  if (bid < 3072) {
    in = w_qkv; out = wqkvT; R = 1024; C = 3072;
    bx = bid % 96; by = bid / 96;
  } else if (bid < 7168) {
    int b = bid - 3072;
    in = w_in; out = winT; R = 1024; C = 4096;
    bx = b % 128; by = b / 128;
  } else {
    int b = bid - 7168;
    in = w_out; out = woutT; R = 5120; C = 1024;
    bx = b % 32; by = b / 32;
  }
  int tx = threadIdx.x & 31, ty = threadIdx.x >> 5;  // 32 x 8
  int r0 = by * 32, c0 = bx * 32;
#pragma unroll
  for (int i = 0; i < 32; i += 8)
    tile[ty + i][tx] = f2bf(in[(size_t)(r0 + ty + i) * C + c0 + tx]);
  __syncthreads();
#pragma unroll
  for (int i = 0; i < 32; i += 8)
    out[(size_t)(c0 + ty + i) * R + r0 + tx] = tile[tx][ty + i];
}

// ---------------- RMSNorm: 8192 rows x 1024, f32 in -> bf16 out ----------------
__global__ __launch_bounds__(256) void rmsnorm_kernel(const float* __restrict__ x,
                                                      const float* __restrict__ w,
                                                      u16* __restrict__ xn) {
  int row = blockIdx.x, t = threadIdx.x;
  const float4* xr = reinterpret_cast<const float4*>(x + (size_t)row * 1024);
  float4 v = xr[t];
  float ss = v.x * v.x + v.y * v.y + v.z * v.z + v.w * v.w;
#pragma unroll
  for (int d = 1; d < 64; d <<= 1) ss += __shfl_xor(ss, d);
  __shared__ float red[4];
  if ((t & 63) == 0) red[t >> 6] = ss;
  __syncthreads();
  float tot = red[0] + red[1] + red[2] + red[3];
  float inv = rsqrtf(tot * (1.0f / 1024.0f) + 1e-6f);
  float4 wv = reinterpret_cast<const float4*>(w)[t];
  u16x4 o;
  o[0] = f2bf(v.x * inv * wv.x);
  o[1] = f2bf(v.y * inv * wv.y);
  o[2] = f2bf(v.z * inv * wv.z);
  o[3] = f2bf(v.w * inv * wv.w);
  *reinterpret_cast<u16x4*>(xn + (size_t)row * 1024 + t * 4) = o;
}

// ============ Pipelined GEMM (R22 schedule, FROZEN): all three GEMMs ========
// BM=256, BN=128, BK=64; 8 waves (4M x 2N). Triple-buffered LDS (144 KB),
// staging 1 tile ahead, counted vmcnt(6) at tile boundary, setprio, raw
// s_barrier, XOR-swizzled rows. Panel-pinned XCD remap (bid%8 == by%8).
// bf16 epilogues (modes 1, 3-q/k) gather 4 CONSECUTIVE columns per lane via
// a per-wave LDS transpose (LDS quiescent after the K-loop), then store one
// u16x4 -> 16 lanes = 128B contiguous = full 64B lines, no write-allocate RMW.
// mode 1: bf16+GELU(tanh); 2: f32; 3: QKV fused epilogue (rope in-lane).
DEV void stage_half(const u16* __restrict__ gbase, int K, int kt, char* dst, int w, int l) {
#pragma unroll
  for (int j = 0; j < 2; ++j) {
    int s = w * 2 + j;
    int row = s * 8 + (l >> 3);
    int ksrc = ((l & 7) ^ (l >> 3)) << 3;
    const u16* src = gbase + (size_t)row * K + kt + ksrc;
    __builtin_amdgcn_global_load_lds(
        (const __attribute__((address_space(1))) unsigned int*)src,
        (__attribute__((address_space(3))) unsigned int*)(dst + s * 1024 + l * 16),
        16, 0, 0);
  }
}

DEV short8 ldfrag(const char* base, int row, int slot) {
  return *reinterpret_cast<const short8*>(base + row * 128 + (((slot ^ (row & 7)) << 4)));
}

__global__ __launch_bounds__(512) void gemm256(const u16* __restrict__ A,
                                               const u16* __restrict__ BT,
                                               const float* __restrict__ bias,
                                               void* __restrict__ Cout,
                                               u16* __restrict__ vTout,
                                               const float* __restrict__ sp,
                                               const float* __restrict__ cp,
                                               int K, int ldc, int mode, int NBX) {
  __shared__ float4 lds_v[9216];  // 147456 B
  char* lds = (char*)lds_v;
  int t = threadIdx.x;
  int w = t >> 6, l = t & 63, c = l & 15, g = l >> 4;
  int wr = w >> 1, wc = w & 1;

  // panel-pinning remap: all NBX blocks of A-panel `by` share XCD by%8.
  int bid = blockIdx.x;
  int x8 = bid & 7, q = bid >> 3;
  int bx = q % NBX;
  int by = (q / NBX) * 8 + x8;

  size_t m0 = (size_t)by * 256, n0 = (size_t)bx * 128;
  const u16* Ab = A + m0 * K;
  const u16* Bb = BT + n0 * K;
  int KT = K >> 6;

  f32x4 zero4 = {0.f, 0.f, 0.f, 0.f};
  f32x4 acc[4][4];
#pragma unroll
  for (int a = 0; a < 4; ++a)
#pragma unroll
    for (int b2 = 0; b2 < 4; ++b2) acc[a][b2] = zero4;

#pragma unroll
  for (int pt = 0; pt < 2; ++pt) {
    int boff = pt * 49152;
    stage_half(Ab, K, pt * 64, lds + boff, w, l);
    stage_half(Ab + (size_t)128 * K, K, pt * 64, lds + boff + 16384, w, l);
    stage_half(Bb, K, pt * 64, lds + boff + 32768, w, l);
  }
  VMW(6);
  __builtin_amdgcn_s_barrier();

  for (int tt = 0; tt < KT; ++tt) {
    const char* Abuf = lds + (tt % 3) * 49152;
    const char* Bbuf = Abuf + 32768;
    int b2off = ((tt + 2) % 3) * 49152;
    int kt2 = (tt + 2) * 64;
    bool pf = (tt + 2 < KT);

    if (pf) {
      stage_half(Ab, K, kt2, lds + b2off, w, l);
      stage_half(Ab + (size_t)128 * K, K, kt2, lds + b2off + 16384, w, l);
    }
    {
      short8 bv[4], av[4];
#pragma unroll
      for (int nj = 0; nj < 4; ++nj) bv[nj] = ldfrag(Bbuf, wc * 64 + 16 * nj + c, g);
#pragma unroll
      for (int mi = 0; mi < 4; ++mi) av[mi] = ldfrag(Abuf, wr * 64 + 16 * mi + c, g);
      __builtin_amdgcn_s_setprio(1);
#pragma unroll
      for (int mi = 0; mi < 4; ++mi)
#pragma unroll
        for (int nj = 0; nj < 4; ++nj)
          acc[mi][nj] = __builtin_amdgcn_mfma_f32_16x16x32_bf16(av[mi], bv[nj], acc[mi][nj], 0, 0, 0);
      __builtin_amdgcn_s_setprio(0);
    }
    __builtin_amdgcn_s_barrier();

    if (pf) stage_half(Bb, K, kt2, lds + b2off + 32768, w, l);
    {
      short8 bv[4], av[4];
#pragma unroll
      for (int nj = 0; nj < 4; ++nj) bv[nj] = ldfrag(Bbuf, wc * 64 + 16 * nj + c, 4 + g);
#pragma unroll
      for (int mi = 0; mi < 4; ++mi) av[mi] = ldfrag(Abuf, wr * 64 + 16 * mi + c, 4 + g);
      __builtin_amdgcn_s_setprio(1);
#pragma unroll
      for (int mi = 0; mi < 4; ++mi)
#pragma unroll
        for (int nj = 0; nj < 4; ++nj)
          acc[mi][nj] = __builtin_amdgcn_mfma_f32_16x16x32_bf16(av[mi], bv[nj], acc[mi][nj], 0, 0, 0);
      __builtin_amdgcn_s_setprio(0);
    }
    if (tt + 1 < KT) {
      if (pf)
        VMW(6);
      else
        VMW(0);
      __builtin_amdgcn_s_barrier();
    }
  }

  // ---- epilogue ----
  // per-wave LDS slice for column-gather: 2 alternating 16x68-f32 slabs
  // (double-slab kills WAR between consecutive mi). LDS is quiescent here
  // (final boundary drained vmcnt to 0; no stages in last iteration).
  float* swbase = (float*)lds + (size_t)w * 2176;
  int colb = (int)n0 + wc * 64 + 4 * c;  // 4 consecutive cols per lane

  if (mode == 3) {
    bool blockV = (n0 >= 2048);  // block-uniform: 2048 % 128 == 0
    if (!blockV) {
      // q/k: LDS gather -> bias -> rope in-lane -> u16x4 full-line store
      float scq = (colb < 1024) ? 0.125f : 1.0f;  // uniform per 64-col group
      float4 bb = *reinterpret_cast<const float4*>(bias + colb);
      int d0 = colb & 63;  // = 4*c
#pragma unroll
      for (int mi = 0; mi < 4; ++mi) {
        float* sw = swbase + (mi & 1) * 1088;
        size_t rbase = m0 + wr * 64 + 16 * mi + 4 * g;
#pragma unroll
        for (int nj = 0; nj < 4; ++nj)
#pragma unroll
          for (int r = 0; r < 4; ++r)
            sw[(4 * g + r) * 68 + 16 * nj + c] = acc[mi][nj][r];
        asm volatile("s_waitcnt lgkmcnt(0)" ::: "memory");
#pragma unroll
        for (int r = 0; r < 4; ++r) {
          float4 f4 = *reinterpret_cast<const float4*>(&sw[(4 * g + r) * 68 + 4 * c]);
          float f0 = f4.x + bb.x, f1 = f4.y + bb.y, f2 = f4.z + bb.z, f3 = f4.w + bb.w;
          int pos = (int)((rbase + r) & 4095);
          float4 sv = *reinterpret_cast<const float4*>(sp + pos * 64 + d0);
          float4 cv = *reinterpret_cast<const float4*>(cp + pos * 64 + d0);
          u16x4 o;
          o[0] = f2bf((f0 * cv.x - f1 * sv.x) * scq);
          o[1] = f2bf((f1 * cv.y + f0 * sv.y) * scq);
          o[2] = f2bf((f2 * cv.z - f3 * sv.z) * scq);
          o[3] = f2bf((f3 * cv.w + f2 * sv.w) * scq);
          *reinterpret_cast<u16x4*>((u16*)Cout + (rbase + r) * (size_t)ldc + colb) = o;
        }
      }
    } else {
      int b16 = ((int)(m0 >> 12)) * 16;
#pragma unroll
      for (int nj = 0; nj < 4; ++nj) {
        int col = (int)n0 + wc * 64 + 16 * nj + c;
        float bvv = bias[col];
        int cv2 = col - 2048;
        int h = cv2 >> 6, d = cv2 & 63;
        u16* vb = vTout + ((size_t)(b16 + h)) * 262144 + (size_t)d * 4096;
#pragma unroll
        for (int mi = 0; mi < 4; ++mi) {
          size_t rbase = m0 + wr * 64 + 16 * mi + 4 * g;
          int s0 = (int)(rbase & 4095);
          u16x4 pk;
#pragma unroll
          for (int r = 0; r < 4; ++r) pk[r] = f2bf(acc[mi][nj][r] + bvv);
          *reinterpret_cast<u16x4*>(vb + s0) = pk;
        }
      }
    }
    return;
  }

  if (mode == 1) {
    // FF: LDS gather -> bias -> gelu -> u16x4 full-line store
    float4 bb = *reinterpret_cast<const float4*>(bias + colb);
#pragma unroll
    for (int mi = 0; mi < 4; ++mi) {
      float* sw = swbase + (mi & 1) * 1088;
      size_t rbase = m0 + wr * 64 + 16 * mi + 4 * g;
#pragma unroll
      for (int nj = 0; nj < 4; ++nj)
#pragma unroll
        for (int r = 0; r < 4; ++r)
          sw[(4 * g + r) * 68 + 16 * nj + c] = acc[mi][nj][r];
      asm volatile("s_waitcnt lgkmcnt(0)" ::: "memory");
#pragma unroll
      for (int r = 0; r < 4; ++r) {
        float4 f4 = *reinterpret_cast<const float4*>(&sw[(4 * g + r) * 68 + 4 * c]);
        u16x4 o;
        o[0] = f2bf(fast_gelu(f4.x + bb.x));
        o[1] = f2bf(fast_gelu(f4.y + bb.y));
        o[2] = f2bf(fast_gelu(f4.z + bb.z));
        o[3] = f2bf(fast_gelu(f4.w + bb.w));
        *reinterpret_cast<u16x4*>((u16*)Cout + (rbase + r) * (size_t)ldc + colb) = o;
      }
    }
    return;
  }

  // mode 2 (OUT, f32): 16 lanes x 4B already cover full 64B lines
#pragma unroll
  for (int nj = 0; nj < 4; ++nj) {
    int col = (int)n0 + wc * 64 + 16 * nj + c;
    float bvv = bias[col];
#pragma unroll
    for (int mi = 0; mi < 4; ++mi) {
      size_t rbase = m0 + wr * 64 + 16 * mi + 4 * g;
#pragma unroll
      for (int r = 0; r < 4; ++r) {
        float f = acc[mi][nj][r] + bvv;
        ((float*)Cout)[(rbase + r) * (size_t)ldc + col] = f;
      }
    }
  }
}

// ------------- sliding-window causal attention (R22 exact) ------------------
// 1 wave per 32-query tile, no barriers. grid = 4096, block = 64.
// qk rows: [q(1024)|k(1024)], stride 2048, pre-roped, q pre-scaled 0.125.
// K[t+1] and V[t] issued early, consumed late (T14). Defer-max (T13).
__global__ __launch_bounds__(64) void attn_kernel(const u16* __restrict__ qk,
                                                  const u16* __restrict__ vT,
                                                  u16* __restrict__ comb) {
  int bid = blockIdx.x;
  int swz = ((bid & 7) << 9) + (bid >> 3);  // 4096/8 = 512 per XCD
  int qt = swz & 127, h = (swz >> 7) & 15, b = swz >> 11;
  int l = threadIdx.x, c = l & 15, g = l >> 4;
  int q0 = qt * 32;
  const u16* qb = qk + (size_t)b * 4096 * 2048 + h * 64;
  const u16* kb = qb + 1024;
  const u16* vt = vT + (size_t)(b * 16 + h) * 64 * 4096;
  __shared__ u16 Pl[32 * 72];

  short8 qf[2][2];
#pragma unroll
  for (int mi = 0; mi < 2; ++mi)
#pragma unroll
    for (int kk = 0; kk < 2; ++kk)
      qf[mi][kk] = *reinterpret_cast<const short8*>(
          qb + (size_t)(q0 + 16 * mi + c) * 2048 + 32 * kk + 8 * g);

  f32x4 zero4 = {0.f, 0.f, 0.f, 0.f};
  f32x4 o[2][4];
  float mr[2][4], lr[2][4];
#pragma unroll
  for (int a = 0; a < 2; ++a)
#pragma unroll
    for (int d2 = 0; d2 < 4; ++d2) {
      o[a][d2] = zero4;
      mr[a][d2] = -1e30f;
      lr[a][d2] = 0.f;
    }

  int t_lo = (q0 >= 480) ? ((q0 - 480) >> 6) : 0;
  int t_hi = (q0 + 31) >> 6;

  short8 kfc[2][4], kfn[2][4], bv[2][4];
#pragma unroll
  for (int kk = 0; kk < 2; ++kk)
#pragma unroll
    for (int nj = 0; nj < 4; ++nj)
      kfc[kk][nj] = *reinterpret_cast<const short8*>(
          kb + (size_t)(t_lo * 64 + 16 * nj + c) * 2048 + 32 * kk + 8 * g);

  for (int tt = t_lo; tt <= t_hi; ++tt) {
    int kt0 = tt * 64;

    // issue V[t] loads (consumed at PV, after softmax)
#pragma unroll
    for (int kk = 0; kk < 2; ++kk)
#pragma unroll
      for (int dj = 0; dj < 4; ++dj)
        bv[kk][dj] = *reinterpret_cast<const short8*>(
            vt + (size_t)(16 * dj + c) * 4096 + kt0 + 32 * kk + 8 * g);

    // issue K[t+1] loads (consumed at the rotate, after PV)
    if (tt < t_hi) {
#pragma unroll
      for (int kk = 0; kk < 2; ++kk)
#pragma unroll
        for (int nj = 0; nj < 4; ++nj)
          kfn[kk][nj] = *reinterpret_cast<const short8*>(
              kb + (size_t)(kt0 + 64 + 16 * nj + c) * 2048 + 32 * kk + 8 * g);
    }

    // QK^T with current (pre-loaded) K frags
    f32x4 s[2][4];
#pragma unroll
    for (int a = 0; a < 2; ++a)
#pragma unroll
      for (int d2 = 0; d2 < 4; ++d2) s[a][d2] = zero4;
#pragma unroll
    for (int kk = 0; kk < 2; ++kk)
#pragma unroll
      for (int mi = 0; mi < 2; ++mi)
#pragma unroll
        for (int nj = 0; nj < 4; ++nj)
          s[mi][nj] = __builtin_amdgcn_mfma_f32_16x16x32_bf16(qf[mi][kk], kfc[kk][nj], s[mi][nj], 0, 0, 0);

    // mask only on the boundary tiles (wave-uniform branch)
    bool mc = (tt == t_hi), mw = (tt == t_lo);
    if (mc | mw) {
#pragma unroll
      for (int mi = 0; mi < 2; ++mi)
#pragma unroll
        for (int nj = 0; nj < 4; ++nj)
#pragma unroll
          for (int r = 0; r < 4; ++r) {
            int qg = q0 + 16 * mi + 4 * g + r;
            int kg = kt0 + 16 * nj + c;
            if ((mc && kg > qg) || (mw && qg - kg >= 512)) s[mi][nj][r] = -1e30f;
          }
    }

    // tile maxima + defer-max decision (wave-uniform)
    float tmv[2][4];
    float dmax = -1e30f;
#pragma unroll
    for (int mi = 0; mi < 2; ++mi)
#pragma unroll
      for (int r = 0; r < 4; ++r) {
        float tm = fmaxf(fmaxf(s[mi][0][r], s[mi][1][r]), fmaxf(s[mi][2][r], s[mi][3][r]));
        tm = redmax16(tm);
        tmv[mi][r] = tm;
        dmax = fmaxf(dmax, tm - mr[mi][r]);
      }
    if (!__all(dmax <= 8.0f)) {
#pragma unroll
      for (int mi = 0; mi < 2; ++mi)
#pragma unroll
        for (int r = 0; r < 4; ++r) {
          float mn = fmaxf(mr[mi][r], tmv[mi][r]);
          float a = __expf(mr[mi][r] - mn);
          mr[mi][r] = mn;
          lr[mi][r] *= a;
#pragma unroll
          for (int dj = 0; dj < 4; ++dj) o[mi][dj][r] *= a;
        }
    }

#pragma unroll
    for (int mi = 0; mi < 2; ++mi)
#pragma unroll
      for (int r = 0; r < 4; ++r) {
        float rs = 0.f;
        u16* pp = &Pl[(16 * mi + 4 * g + r) * 72 + c];
#pragma unroll
        for (int nj = 0; nj < 4; ++nj) {
          float p = __expf(s[mi][nj][r] - mr[mi][r]);
          rs += p;
          pp[16 * nj] = f2bf(p);  // natural k order, imm-offset ds_write_b16
        }
        rs = redsum16(rs);
        lr[mi][r] += rs;
      }

    // PV: A-frag from Pl, B-frag = V regs issued before softmax
#pragma unroll
    for (int kk = 0; kk < 2; ++kk) {
      short8 pa[2];
#pragma unroll
      for (int mi = 0; mi < 2; ++mi)
        pa[mi] = *reinterpret_cast<const short8*>(&Pl[(16 * mi + c) * 72 + 32 * kk + 8 * g]);
#pragma unroll
      for (int mi = 0; mi < 2; ++mi)
#pragma unroll
        for (int dj = 0; dj < 4; ++dj)
          o[mi][dj] = __builtin_amdgcn_mfma_f32_16x16x32_bf16(pa[mi], bv[kk][dj], o[mi][dj], 0, 0, 0);
    }

    // rotate: consume K[t+1] loads (they were in flight the whole tile)
    if (tt < t_hi) {
#pragma unroll
      for (int kk = 0; kk < 2; ++kk)
#pragma unroll
        for (int nj = 0; nj < 4; ++nj) kfc[kk][nj] = kfn[kk][nj];
    }
  }

  u16* ob = comb + (size_t)(b * 4096 + q0) * 5120 + h * 64;
#pragma unroll
  for (int mi = 0; mi < 2; ++mi)
#pragma unroll
    for (int r = 0; r < 4; ++r) {
      float inv = __builtin_amdgcn_rcpf(lr[mi][r]);
#pragma unroll
      for (int dj = 0; dj < 4; ++dj)
        ob[(size_t)(16 * mi + 4 * g + r) * 5120 + 16 * dj + c] = f2bf(o[mi][dj][r] * inv);
    }
}

// ---------------- launch ----------------
extern "C" void kernel_launch(void* const* d_in, const int* in_sizes, int n_in,
                              void* d_out, int out_size, void* d_ws, size_t ws_size,
                              hipStream_t stream) {
  const float* x = (const float*)d_in[0];
  const float* sinp = (const float*)d_in[1];
  const float* cosp = (const float*)d_in[2];
  const float* norm_w = (const float*)d_in[3];
  const float* w_qkv = (const float*)d_in[4];
  const float* b_qkv = (const float*)d_in[5];
  const float* w_in = (const float*)d_in[6];
  const float* b_in = (const float*)d_in[7];
  const float* w_out = (const float*)d_in[8];
  const float* b_out = (const float*)d_in[9];
  float* out = (float*)d_out;

  char* ws = (char*)d_ws;
  u16* xn = (u16*)(ws);                        // 8192*1024*2      = 16,777,216
  u16* qk = (u16*)(ws + 16777216);             // 8192*2048*2      = 33,554,432
  u16* vT = (u16*)(ws + 50331648);             // 32*64*4096*2     = 16,777,216
  u16* comb = (u16*)(ws + 67108864);           // 8192*5120*2      = 83,886,080
  u16* wqkvT = (u16*)(ws + 150994944);         // 3072*1024*2      = 6,291,456
  u16* winT = (u16*)(ws + 157286400);          // 4096*1024*2      = 8,388,608
  u16* woutT = (u16*)(ws + 165675008);         // 1024*5120*2      = 10,485,760

  transpose_all<<<12288, 256, 0, stream>>>(w_qkv, w_in, w_out, wqkvT, winT, woutT);

  rmsnorm_kernel<<<8192, 256, 0, stream>>>(x, norm_w, xn);

  // qkv GEMM, fused epilogue: q/k -> rope+scale -> qk[2048]; V -> vT directly
  gemm256<<<768, 512, 0, stream>>>(
      xn, wqkvT, b_qkv, qk, vT, sinp, cosp, 1024, 2048, 3, 24);

  // ff = gelu(xn @ w_in + b_in) -> comb cols [1024, 5120)  (last use of xn)
  gemm256<<<1024, 512, 0, stream>>>(
      xn, winT, b_in, comb + 1024, nullptr, nullptr, nullptr, 1024, 5120, 1, 32);

  attn_kernel<<<4096, 64, 0, stream>>>(qk, vT, comb);

  // out = comb @ w_out + b_out  (f32 out)
  gemm256<<<256, 512, 0, stream>>>(
      comb, woutT, b_out, out, nullptr, nullptr, nullptr, 5120, 1024, 2, 8);
}

// Round 27
// 333.067 us; speedup vs baseline: 1.1323x; 1.0109x over previous
//
#include <hip/hip_runtime.h>

typedef unsigned short u16;
typedef __attribute__((ext_vector_type(8))) short short8;
typedef __attribute__((ext_vector_type(4))) unsigned short u16x4;
typedef __attribute__((ext_vector_type(4))) float f32x4;

#define DEV __device__ __forceinline__
#define VMW(n) asm volatile("s_waitcnt vmcnt(" #n ")" ::: "memory")

DEV float bf2f(u16 u) { return __uint_as_float(((unsigned int)u) << 16); }
DEV u16 f2bf(float f) {
  unsigned int u = __float_as_uint(f);
  u += 0x7FFF + ((u >> 16) & 1);
  return (u16)(u >> 16);
}

// tanh-form GELU: 0.5x(1+tanh(a(x+bx^3))) = x - x*rcp(exp(2a(x+bx^3))+1)
DEV float fast_gelu(float x) {
  float z2 = 1.5957691216f * x * (1.0f + 0.044715f * x * x);  // 2*a*(x+b x^3)
  float e = __expf(z2);
  float r = __builtin_amdgcn_rcpf(e + 1.0f);
  return x - x * r;
}

DEV float redmax16(float v) {
  v = fmaxf(v, __shfl_xor(v, 1));
  v = fmaxf(v, __shfl_xor(v, 2));
  v = fmaxf(v, __shfl_xor(v, 4));
  v = fmaxf(v, __shfl_xor(v, 8));
  return v;
}
DEV float redsum16(float v) {
  v += __shfl_xor(v, 1);
  v += __shfl_xor(v, 2);
  v += __shfl_xor(v, 4);
  v += __shfl_xor(v, 8);
  return v;
}

// ------ fused transpose + cast f32 -> bf16 for all three weight matrices ----
__global__ __launch_bounds__(256) void transpose_all(const float* __restrict__ w_qkv,
                                                     const float* __restrict__ w_in,
                                                     const float* __restrict__ w_out,
                                                     u16* __restrict__ wqkvT,
                                                     u16* __restrict__ winT,
                                                     u16* __restrict__ woutT) {
  __shared__ u16 tile[32][33];
  int bid = blockIdx.x;
  const float* in;
  u16* out;
  int R, C, bx, by;
  if (bid < 3072) {
    in = w_qkv; out = wqkvT; R = 1024; C = 3072;
    bx = bid % 96; by = bid / 96;
  } else if (bid < 7168) {
    int b = bid - 3072;
    in = w_in; out = winT; R = 1024; C = 4096;
    bx = b % 128; by = b / 128;
  } else {
    int b = bid - 7168;
    in = w_out; out = woutT; R = 5120; C = 1024;
    bx = b % 32; by = b / 32;
  }
  int tx = threadIdx.x & 31, ty = threadIdx.x >> 5;  // 32 x 8
  int r0 = by * 32, c0 = bx * 32;
#pragma unroll
  for (int i = 0; i < 32; i += 8)
    tile[ty + i][tx] = f2bf(in[(size_t)(r0 + ty + i) * C + c0 + tx]);
  __syncthreads();
#pragma unroll
  for (int i = 0; i < 32; i += 8)
    out[(size_t)(c0 + ty + i) * R + r0 + tx] = tile[tx][ty + i];
}

// ---------------- RMSNorm: 8192 rows x 1024, f32 in -> bf16 out ----------------
__global__ __launch_bounds__(256) void rmsnorm_kernel(const float* __restrict__ x,
                                                      const float* __restrict__ w,
                                                      u16* __restrict__ xn) {
  int row = blockIdx.x, t = threadIdx.x;
  const float4* xr = reinterpret_cast<const float4*>(x + (size_t)row * 1024);
  float4 v = xr[t];
  float ss = v.x * v.x + v.y * v.y + v.z * v.z + v.w * v.w;
#pragma unroll
  for (int d = 1; d < 64; d <<= 1) ss += __shfl_xor(ss, d);
  __shared__ float red[4];
  if ((t & 63) == 0) red[t >> 6] = ss;
  __syncthreads();
  float tot = red[0] + red[1] + red[2] + red[3];
  float inv = rsqrtf(tot * (1.0f / 1024.0f) + 1e-6f);
  float4 wv = reinterpret_cast<const float4*>(w)[t];
  u16x4 o;
  o[0] = f2bf(v.x * inv * wv.x);
  o[1] = f2bf(v.y * inv * wv.y);
  o[2] = f2bf(v.z * inv * wv.z);
  o[3] = f2bf(v.w * inv * wv.w);
  *reinterpret_cast<u16x4*>(xn + (size_t)row * 1024 + t * 4) = o;
}

// ============ Pipelined GEMM (R26 schedule, FROZEN) =========================
// BM=256, BN=128, BK=64; 8 waves (4M x 2N). Triple-buffered LDS (144 KB),
// staging 1 tile ahead, counted vmcnt(6) at tile boundary, setprio, raw
// s_barrier, XOR-swizzled rows. Panel-pinned XCD remap (bid%8 == by%8).
// bf16 epilogues gather 4 CONSECUTIVE columns per lane via a per-wave LDS
// transpose (LDS quiescent after the K-loop) -> u16x4 full-line stores.
// mode 1: bf16+GELU; 2: f32; 3: QKV fused epilogue (rope in-lane, V->vT);
// mode 4: MERGED QKV+FF (q<96 -> QKV sub-grid / else FF sub-grid; both K=1024,
//         same A; block-uniform selection of B/bias/C/ldc/epilogue).
DEV void stage_half(const u16* __restrict__ gbase, int K, int kt, char* dst, int w, int l) {
#pragma unroll
  for (int j = 0; j < 2; ++j) {
    int s = w * 2 + j;
    int row = s * 8 + (l >> 3);
    int ksrc = ((l & 7) ^ (l >> 3)) << 3;
    const u16* src = gbase + (size_t)row * K + kt + ksrc;
    __builtin_amdgcn_global_load_lds(
        (const __attribute__((address_space(1))) unsigned int*)src,
        (__attribute__((address_space(3))) unsigned int*)(dst + s * 1024 + l * 16),
        16, 0, 0);
  }
}

DEV short8 ldfrag(const char* base, int row, int slot) {
  return *reinterpret_cast<const short8*>(base + row * 128 + (((slot ^ (row & 7)) << 4)));
}

__global__ __launch_bounds__(512) void gemm256(const u16* __restrict__ A,
                                               const u16* __restrict__ BT,
                                               const float* __restrict__ bias,
                                               void* __restrict__ Cout,
                                               u16* __restrict__ vTout,
                                               const float* __restrict__ sp,
                                               const float* __restrict__ cp,
                                               const u16* __restrict__ BT2,
                                               const float* __restrict__ bias2,
                                               void* __restrict__ Cout2,
                                               int K, int ldc, int mode, int NBX) {
  __shared__ float4 lds_v[9216];  // 147456 B
  char* lds = (char*)lds_v;
  int t = threadIdx.x;
  int w = t >> 6, l = t & 63, c = l & 15, g = l >> 4;
  int wr = w >> 1, wc = w & 1;

  // panel-pinning remap: all blocks of A-panel `by` share XCD by%8.
  int bid = blockIdx.x;
  int x8 = bid & 7, q = bid >> 3;
  int emode = mode, bx, by, ldcc = ldc;
  const u16* Bbase = BT;
  const float* biasp = bias;
  void* Cp = Cout;
  if (mode == 4) {  // merged QKV (q<96, NBX=24) + FF (q>=96, NBX=32)
    if (q < 96) {
      emode = 3; bx = q % 24; by = (q / 24) * 8 + x8; ldcc = 2048;
    } else {
      int q2 = q - 96;
      emode = 1; bx = q2 % 32; by = (q2 / 32) * 8 + x8; ldcc = 5120;
      Bbase = BT2; biasp = bias2; Cp = Cout2;
    }
  } else {
    bx = q % NBX;
    by = (q / NBX) * 8 + x8;
  }

  size_t m0 = (size_t)by * 256, n0 = (size_t)bx * 128;
  const u16* Ab = A + m0 * K;
  const u16* Bb = Bbase + n0 * K;
  int KT = K >> 6;

  f32x4 zero4 = {0.f, 0.f, 0.f, 0.f};
  f32x4 acc[4][4];
#pragma unroll
  for (int a = 0; a < 4; ++a)
#pragma unroll
    for (int b2 = 0; b2 < 4; ++b2) acc[a][b2] = zero4;

#pragma unroll
  for (int pt = 0; pt < 2; ++pt) {
    int boff = pt * 49152;
    stage_half(Ab, K, pt * 64, lds + boff, w, l);
    stage_half(Ab + (size_t)128 * K, K, pt * 64, lds + boff + 16384, w, l);
    stage_half(Bb, K, pt * 64, lds + boff + 32768, w, l);
  }
  VMW(6);
  __builtin_amdgcn_s_barrier();

  for (int tt = 0; tt < KT; ++tt) {
    const char* Abuf = lds + (tt % 3) * 49152;
    const char* Bbuf = Abuf + 32768;
    int b2off = ((tt + 2) % 3) * 49152;
    int kt2 = (tt + 2) * 64;
    bool pf = (tt + 2 < KT);

    if (pf) {
      stage_half(Ab, K, kt2, lds + b2off, w, l);
      stage_half(Ab + (size_t)128 * K, K, kt2, lds + b2off + 16384, w, l);
    }
    {
      short8 bv[4], av[4];
#pragma unroll
      for (int nj = 0; nj < 4; ++nj) bv[nj] = ldfrag(Bbuf, wc * 64 + 16 * nj + c, g);
#pragma unroll
      for (int mi = 0; mi < 4; ++mi) av[mi] = ldfrag(Abuf, wr * 64 + 16 * mi + c, g);
      __builtin_amdgcn_s_setprio(1);
#pragma unroll
      for (int mi = 0; mi < 4; ++mi)
#pragma unroll
        for (int nj = 0; nj < 4; ++nj)
          acc[mi][nj] = __builtin_amdgcn_mfma_f32_16x16x32_bf16(av[mi], bv[nj], acc[mi][nj], 0, 0, 0);
      __builtin_amdgcn_s_setprio(0);
    }
    __builtin_amdgcn_s_barrier();

    if (pf) stage_half(Bb, K, kt2, lds + b2off + 32768, w, l);
    {
      short8 bv[4], av[4];
#pragma unroll
      for (int nj = 0; nj < 4; ++nj) bv[nj] = ldfrag(Bbuf, wc * 64 + 16 * nj + c, 4 + g);
#pragma unroll
      for (int mi = 0; mi < 4; ++mi) av[mi] = ldfrag(Abuf, wr * 64 + 16 * mi + c, 4 + g);
      __builtin_amdgcn_s_setprio(1);
#pragma unroll
      for (int mi = 0; mi < 4; ++mi)
#pragma unroll
        for (int nj = 0; nj < 4; ++nj)
          acc[mi][nj] = __builtin_amdgcn_mfma_f32_16x16x32_bf16(av[mi], bv[nj], acc[mi][nj], 0, 0, 0);
      __builtin_amdgcn_s_setprio(0);
    }
    if (tt + 1 < KT) {
      if (pf)
        VMW(6);
      else
        VMW(0);
      __builtin_amdgcn_s_barrier();
    }
  }

  // ---- epilogue ----
  // per-wave LDS slice for column-gather: 2 alternating 16x68-f32 slabs.
  // LDS quiescent here (final boundary drained vmcnt to 0).
  float* swbase = (float*)lds + (size_t)w * 2176;
  int colb = (int)n0 + wc * 64 + 4 * c;  // 4 consecutive cols per lane

  if (emode == 3) {
    bool blockV = (n0 >= 2048);  // block-uniform: 2048 % 128 == 0
    if (!blockV) {
      // q/k: LDS gather -> bias -> rope in-lane -> u16x4 full-line store
      float scq = (colb < 1024) ? 0.125f : 1.0f;  // uniform per 64-col group
      float4 bb = *reinterpret_cast<const float4*>(biasp + colb);
      int d0 = colb & 63;  // = 4*c
#pragma unroll
      for (int mi = 0; mi < 4; ++mi) {
        float* sw = swbase + (mi & 1) * 1088;
        size_t rbase = m0 + wr * 64 + 16 * mi + 4 * g;
#pragma unroll
        for (int nj = 0; nj < 4; ++nj)
#pragma unroll
          for (int r = 0; r < 4; ++r)
            sw[(4 * g + r) * 68 + 16 * nj + c] = acc[mi][nj][r];
        asm volatile("s_waitcnt lgkmcnt(0)" ::: "memory");
#pragma unroll
        for (int r = 0; r < 4; ++r) {
          float4 f4 = *reinterpret_cast<const float4*>(&sw[(4 * g + r) * 68 + 4 * c]);
          float f0 = f4.x + bb.x, f1 = f4.y + bb.y, f2 = f4.z + bb.z, f3 = f4.w + bb.w;
          int pos = (int)((rbase + r) & 4095);
          float4 sv = *reinterpret_cast<const float4*>(sp + pos * 64 + d0);
          float4 cv = *reinterpret_cast<const float4*>(cp + pos * 64 + d0);
          u16x4 o;
          o[0] = f2bf((f0 * cv.x - f1 * sv.x) * scq);
          o[1] = f2bf((f1 * cv.y + f0 * sv.y) * scq);
          o[2] = f2bf((f2 * cv.z - f3 * sv.z) * scq);
          o[3] = f2bf((f3 * cv.w + f2 * sv.w) * scq);
          *reinterpret_cast<u16x4*>((u16*)Cp + (rbase + r) * (size_t)ldcc + colb) = o;
        }
      }
    } else {
      int b16 = ((int)(m0 >> 12)) * 16;
#pragma unroll
      for (int nj = 0; nj < 4; ++nj) {
        int col = (int)n0 + wc * 64 + 16 * nj + c;
        float bvv = biasp[col];
        int cv2 = col - 2048;
        int h = cv2 >> 6, d = cv2 & 63;
        u16* vb = vTout + ((size_t)(b16 + h)) * 262144 + (size_t)d * 4096;
#pragma unroll
        for (int mi = 0; mi < 4; ++mi) {
          size_t rbase = m0 + wr * 64 + 16 * mi + 4 * g;
          int s0 = (int)(rbase & 4095);
          u16x4 pk;
#pragma unroll
          for (int r = 0; r < 4; ++r) pk[r] = f2bf(acc[mi][nj][r] + bvv);
          *reinterpret_cast<u16x4*>(vb + s0) = pk;
        }
      }
    }
    return;
  }

  if (emode == 1) {
    // FF: LDS gather -> bias -> gelu -> u16x4 full-line store
    float4 bb = *reinterpret_cast<const float4*>(biasp + colb);
#pragma unroll
    for (int mi = 0; mi < 4; ++mi) {
      float* sw = swbase + (mi & 1) * 1088;
      size_t rbase = m0 + wr * 64 + 16 * mi + 4 * g;
#pragma unroll
      for (int nj = 0; nj < 4; ++nj)
#pragma unroll
        for (int r = 0; r < 4; ++r)
          sw[(4 * g + r) * 68 + 16 * nj + c] = acc[mi][nj][r];
      asm volatile("s_waitcnt lgkmcnt(0)" ::: "memory");
#pragma unroll
      for (int r = 0; r < 4; ++r) {
        float4 f4 = *reinterpret_cast<const float4*>(&sw[(4 * g + r) * 68 + 4 * c]);
        u16x4 o;
        o[0] = f2bf(fast_gelu(f4.x + bb.x));
        o[1] = f2bf(fast_gelu(f4.y + bb.y));
        o[2] = f2bf(fast_gelu(f4.z + bb.z));
        o[3] = f2bf(fast_gelu(f4.w + bb.w));
        *reinterpret_cast<u16x4*>((u16*)Cp + (rbase + r) * (size_t)ldcc + colb) = o;
      }
    }
    return;
  }

  // emode 2 (OUT, f32): 16 lanes x 4B already cover full 64B lines
#pragma unroll
  for (int nj = 0; nj < 4; ++nj) {
    int col = (int)n0 + wc * 64 + 16 * nj + c;
    float bvv = biasp[col];
#pragma unroll
    for (int mi = 0; mi < 4; ++mi) {
      size_t rbase = m0 + wr * 64 + 16 * mi + 4 * g;
#pragma unroll
      for (int r = 0; r < 4; ++r) {
        float f = acc[mi][nj][r] + bvv;
        ((float*)Cp)[(rbase + r) * (size_t)ldcc + col] = f;
      }
    }
  }
}

// ------------- sliding-window causal attention (R22 exact) ------------------
// 1 wave per 32-query tile, no barriers. grid = 4096, block = 64.
// qk rows: [q(1024)|k(1024)], stride 2048, pre-roped, q pre-scaled 0.125.
// K[t+1] and V[t] issued early, consumed late (T14). Defer-max (T13).
__global__ __launch_bounds__(64) void attn_kernel(const u16* __restrict__ qk,
                                                  const u16* __restrict__ vT,
                                                  u16* __restrict__ comb) {
  int bid = blockIdx.x;
  int swz = ((bid & 7) << 9) + (bid >> 3);  // 4096/8 = 512 per XCD
  int qt = swz & 127, h = (swz >> 7) & 15, b = swz >> 11;
  int l = threadIdx.x, c = l & 15, g = l >> 4;
  int q0 = qt * 32;
  const u16* qb = qk + (size_t)b * 4096 * 2048 + h * 64;
  const u16* kb = qb + 1024;
  const u16* vt = vT + (size_t)(b * 16 + h) * 64 * 4096;
  __shared__ u16 Pl[32 * 72];

  short8 qf[2][2];
#pragma unroll
  for (int mi = 0; mi < 2; ++mi)
#pragma unroll
    for (int kk = 0; kk < 2; ++kk)
      qf[mi][kk] = *reinterpret_cast<const short8*>(
          qb + (size_t)(q0 + 16 * mi + c) * 2048 + 32 * kk + 8 * g);

  f32x4 zero4 = {0.f, 0.f, 0.f, 0.f};
  f32x4 o[2][4];
  float mr[2][4], lr[2][4];
#pragma unroll
  for (int a = 0; a < 2; ++a)
#pragma unroll
    for (int d2 = 0; d2 < 4; ++d2) {
      o[a][d2] = zero4;
      mr[a][d2] = -1e30f;
      lr[a][d2] = 0.f;
    }

  int t_lo = (q0 >= 480) ? ((q0 - 480) >> 6) : 0;
  int t_hi = (q0 + 31) >> 6;

  short8 kfc[2][4], kfn[2][4], bv[2][4];
#pragma unroll
  for (int kk = 0; kk < 2; ++kk)
#pragma unroll
    for (int nj = 0; nj < 4; ++nj)
      kfc[kk][nj] = *reinterpret_cast<const short8*>(
          kb + (size_t)(t_lo * 64 + 16 * nj + c) * 2048 + 32 * kk + 8 * g);

  for (int tt = t_lo; tt <= t_hi; ++tt) {
    int kt0 = tt * 64;

    // issue V[t] loads (consumed at PV, after softmax)
#pragma unroll
    for (int kk = 0; kk < 2; ++kk)
#pragma unroll
      for (int dj = 0; dj < 4; ++dj)
        bv[kk][dj] = *reinterpret_cast<const short8*>(
            vt + (size_t)(16 * dj + c) * 4096 + kt0 + 32 * kk + 8 * g);

    // issue K[t+1] loads (consumed at the rotate, after PV)
    if (tt < t_hi) {
#pragma unroll
      for (int kk = 0; kk < 2; ++kk)
#pragma unroll
        for (int nj = 0; nj < 4; ++nj)
          kfn[kk][nj] = *reinterpret_cast<const short8*>(
              kb + (size_t)(kt0 + 64 + 16 * nj + c) * 2048 + 32 * kk + 8 * g);
    }

    // QK^T with current (pre-loaded) K frags
    f32x4 s[2][4];
#pragma unroll
    for (int a = 0; a < 2; ++a)
#pragma unroll
      for (int d2 = 0; d2 < 4; ++d2) s[a][d2] = zero4;
#pragma unroll
    for (int kk = 0; kk < 2; ++kk)
#pragma unroll
      for (int mi = 0; mi < 2; ++mi)
#pragma unroll
        for (int nj = 0; nj < 4; ++nj)
          s[mi][nj] = __builtin_amdgcn_mfma_f32_16x16x32_bf16(qf[mi][kk], kfc[kk][nj], s[mi][nj], 0, 0, 0);

    // mask only on the boundary tiles (wave-uniform branch)
    bool mc = (tt == t_hi), mw = (tt == t_lo);
    if (mc | mw) {
#pragma unroll
      for (int mi = 0; mi < 2; ++mi)
#pragma unroll
        for (int nj = 0; nj < 4; ++nj)
#pragma unroll
          for (int r = 0; r < 4; ++r) {
            int qg = q0 + 16 * mi + 4 * g + r;
            int kg = kt0 + 16 * nj + c;
            if ((mc && kg > qg) || (mw && qg - kg >= 512)) s[mi][nj][r] = -1e30f;
          }
    }

    // tile maxima + defer-max decision (wave-uniform)
    float tmv[2][4];
    float dmax = -1e30f;
#pragma unroll
    for (int mi = 0; mi < 2; ++mi)
#pragma unroll
      for (int r = 0; r < 4; ++r) {
        float tm = fmaxf(fmaxf(s[mi][0][r], s[mi][1][r]), fmaxf(s[mi][2][r], s[mi][3][r]));
        tm = redmax16(tm);
        tmv[mi][r] = tm;
        dmax = fmaxf(dmax, tm - mr[mi][r]);
      }
    if (!__all(dmax <= 8.0f)) {
#pragma unroll
      for (int mi = 0; mi < 2; ++mi)
#pragma unroll
        for (int r = 0; r < 4; ++r) {
          float mn = fmaxf(mr[mi][r], tmv[mi][r]);
          float a = __expf(mr[mi][r] - mn);
          mr[mi][r] = mn;
          lr[mi][r] *= a;
#pragma unroll
          for (int dj = 0; dj < 4; ++dj) o[mi][dj][r] *= a;
        }
    }

#pragma unroll
    for (int mi = 0; mi < 2; ++mi)
#pragma unroll
      for (int r = 0; r < 4; ++r) {
        float rs = 0.f;
        u16* pp = &Pl[(16 * mi + 4 * g + r) * 72 + c];
#pragma unroll
        for (int nj = 0; nj < 4; ++nj) {
          float p = __expf(s[mi][nj][r] - mr[mi][r]);
          rs += p;
          pp[16 * nj] = f2bf(p);  // natural k order, imm-offset ds_write_b16
        }
        rs = redsum16(rs);
        lr[mi][r] += rs;
      }

    // PV: A-frag from Pl, B-frag = V regs issued before softmax
#pragma unroll
    for (int kk = 0; kk < 2; ++kk) {
      short8 pa[2];
#pragma unroll
      for (int mi = 0; mi < 2; ++mi)
        pa[mi] = *reinterpret_cast<const short8*>(&Pl[(16 * mi + c) * 72 + 32 * kk + 8 * g]);
#pragma unroll
      for (int mi = 0; mi < 2; ++mi)
#pragma unroll
        for (int dj = 0; dj < 4; ++dj)
          o[mi][dj] = __builtin_amdgcn_mfma_f32_16x16x32_bf16(pa[mi], bv[kk][dj], o[mi][dj], 0, 0, 0);
    }

    // rotate: consume K[t+1] loads (they were in flight the whole tile)
    if (tt < t_hi) {
#pragma unroll
      for (int kk = 0; kk < 2; ++kk)
#pragma unroll
        for (int nj = 0; nj < 4; ++nj) kfc[kk][nj] = kfn[kk][nj];
    }
  }

  u16* ob = comb + (size_t)(b * 4096 + q0) * 5120 + h * 64;
#pragma unroll
  for (int mi = 0; mi < 2; ++mi)
#pragma unroll
    for (int r = 0; r < 4; ++r) {
      float inv = __builtin_amdgcn_rcpf(lr[mi][r]);
#pragma unroll
      for (int dj = 0; dj < 4; ++dj)
        ob[(size_t)(16 * mi + 4 * g + r) * 5120 + 16 * dj + c] = f2bf(o[mi][dj][r] * inv);
    }
}

// ---------------- launch ----------------
extern "C" void kernel_launch(void* const* d_in, const int* in_sizes, int n_in,
                              void* d_out, int out_size, void* d_ws, size_t ws_size,
                              hipStream_t stream) {
  const float* x = (const float*)d_in[0];
  const float* sinp = (const float*)d_in[1];
  const float* cosp = (const float*)d_in[2];
  const float* norm_w = (const float*)d_in[3];
  const float* w_qkv = (const float*)d_in[4];
  const float* b_qkv = (const float*)d_in[5];
  const float* w_in = (const float*)d_in[6];
  const float* b_in = (const float*)d_in[7];
  const float* w_out = (const float*)d_in[8];
  const float* b_out = (const float*)d_in[9];
  float* out = (float*)d_out;

  char* ws = (char*)d_ws;
  u16* xn = (u16*)(ws);                        // 8192*1024*2      = 16,777,216
  u16* qk = (u16*)(ws + 16777216);             // 8192*2048*2      = 33,554,432
  u16* vT = (u16*)(ws + 50331648);             // 32*64*4096*2     = 16,777,216
  u16* comb = (u16*)(ws + 67108864);           // 8192*5120*2      = 83,886,080
  u16* wqkvT = (u16*)(ws + 150994944);         // 3072*1024*2      = 6,291,456
  u16* winT = (u16*)(ws + 157286400);          // 4096*1024*2      = 8,388,608
  u16* woutT = (u16*)(ws + 165675008);         // 1024*5120*2      = 10,485,760

  transpose_all<<<12288, 256, 0, stream>>>(w_qkv, w_in, w_out, wqkvT, winT, woutT);

  rmsnorm_kernel<<<8192, 256, 0, stream>>>(x, norm_w, xn);

  // MERGED QKV + FF (mode 4): q<96 -> QKV (rope+scale -> qk; V -> vT),
  // q>=96 -> FF (gelu -> comb cols [1024,5120)). Both K=1024, same A (xn).
  gemm256<<<1792, 512, 0, stream>>>(
      xn, wqkvT, b_qkv, qk, vT, sinp, cosp, winT, b_in, comb + 1024,
      1024, 0, 4, 0);

  attn_kernel<<<4096, 64, 0, stream>>>(qk, vT, comb);

  // out = comb @ w_out + b_out  (f32 out)
  gemm256<<<256, 512, 0, stream>>>(
      comb, woutT, b_out, out, nullptr, nullptr, nullptr, nullptr, nullptr, nullptr,
      5120, 1024, 2, 8);
}

// Round 28
// 329.054 us; speedup vs baseline: 1.1461x; 1.0122x over previous
//
#include <hip/hip_runtime.h>

typedef unsigned short u16;
typedef __attribute__((ext_vector_type(8))) short short8;
typedef __attribute__((ext_vector_type(4))) unsigned short u16x4;
typedef __attribute__((ext_vector_type(4))) float f32x4;

#define DEV __device__ __forceinline__
#define VMW(n) asm volatile("s_waitcnt vmcnt(" #n ")" ::: "memory")

DEV float bf2f(u16 u) { return __uint_as_float(((unsigned int)u) << 16); }
DEV u16 f2bf(float f) {
  unsigned int u = __float_as_uint(f);
  u += 0x7FFF + ((u >> 16) & 1);
  return (u16)(u >> 16);
}

// tanh-form GELU: 0.5x(1+tanh(a(x+bx^3))) = x - x*rcp(exp(2a(x+bx^3))+1)
DEV float fast_gelu(float x) {
  float z2 = 1.5957691216f * x * (1.0f + 0.044715f * x * x);  // 2*a*(x+b x^3)
  float e = __expf(z2);
  float r = __builtin_amdgcn_rcpf(e + 1.0f);
  return x - x * r;
}

DEV float redmax16(float v) {
  v = fmaxf(v, __shfl_xor(v, 1));
  v = fmaxf(v, __shfl_xor(v, 2));
  v = fmaxf(v, __shfl_xor(v, 4));
  v = fmaxf(v, __shfl_xor(v, 8));
  return v;
}
DEV float redsum16(float v) {
  v += __shfl_xor(v, 1);
  v += __shfl_xor(v, 2);
  v += __shfl_xor(v, 4);
  v += __shfl_xor(v, 8);
  return v;
}

// ---- merged prep: weight transposes (bid<12288) + RMSNorm (bid>=12288) ----
// transpose sub-grid: [0,3072) w_qkv (1024x3072), [3072,7168) w_in
// (1024x4096), [7168,12288) w_out (5120x1024); 32x32 tiles.
// rmsnorm sub-grid: rows 0..8191 of x (f32) -> xn (bf16).
__global__ __launch_bounds__(256) void prep_all(const float* __restrict__ w_qkv,
                                                const float* __restrict__ w_in,
                                                const float* __restrict__ w_out,
                                                u16* __restrict__ wqkvT,
                                                u16* __restrict__ winT,
                                                u16* __restrict__ woutT,
                                                const float* __restrict__ x,
                                                const float* __restrict__ nw,
                                                u16* __restrict__ xn) {
  __shared__ u16 tile[32][33];
  __shared__ float red[4];
  int bid = blockIdx.x;
  if (bid >= 12288) {
    int row = bid - 12288, t = threadIdx.x;
    const float4* xr = reinterpret_cast<const float4*>(x + (size_t)row * 1024);
    float4 v = xr[t];
    float ss = v.x * v.x + v.y * v.y + v.z * v.z + v.w * v.w;
#pragma unroll
    for (int d = 1; d < 64; d <<= 1) ss += __shfl_xor(ss, d);
    if ((t & 63) == 0) red[t >> 6] = ss;
    __syncthreads();
    float tot = red[0] + red[1] + red[2] + red[3];
    float inv = rsqrtf(tot * (1.0f / 1024.0f) + 1e-6f);
    float4 wv = reinterpret_cast<const float4*>(nw)[t];
    u16x4 o;
    o[0] = f2bf(v.x * inv * wv.x);
    o[1] = f2bf(v.y * inv * wv.y);
    o[2] = f2bf(v.z * inv * wv.z);
    o[3] = f2bf(v.w * inv * wv.w);
    *reinterpret_cast<u16x4*>(xn + (size_t)row * 1024 + t * 4) = o;
    return;
  }
  const float* in;
  u16* out;
  int R, C, bx, by;
  if (bid < 3072) {
    in = w_qkv; out = wqkvT; R = 1024; C = 3072;
    bx = bid % 96; by = bid / 96;
  } else if (bid < 7168) {
    int b = bid - 3072;
    in = w_in; out = winT; R = 1024; C = 4096;
    bx = b % 128; by = b / 128;
  } else {
    int b = bid - 7168;
    in = w_out; out = woutT; R = 5120; C = 1024;
    bx = b % 32; by = b / 32;
  }
  int tx = threadIdx.x & 31, ty = threadIdx.x >> 5;  // 32 x 8
  int r0 = by * 32, c0 = bx * 32;
#pragma unroll
  for (int i = 0; i < 32; i += 8)
    tile[ty + i][tx] = f2bf(in[(size_t)(r0 + ty + i) * C + c0 + tx]);
  __syncthreads();
#pragma unroll
  for (int i = 0; i < 32; i += 8)
    out[(size_t)(c0 + ty + i) * R + r0 + tx] = tile[tx][ty + i];
}

// ============ Pipelined GEMM (R27 exact, FROZEN) ============================
// BM=256, BN=128, BK=64; 8 waves (4M x 2N). Triple-buffered LDS (144 KB),
// staging 1 tile ahead, counted vmcnt(6) at tile boundary, setprio, raw
// s_barrier, XOR-swizzled rows. Panel-pinned XCD remap (bid%8 == by%8).
// bf16 epilogues gather 4 CONSECUTIVE columns per lane via a per-wave LDS
// transpose (LDS quiescent after the K-loop) -> u16x4 full-line stores.
// mode 1: bf16+GELU; 2: f32; 3: QKV fused epilogue (rope in-lane, V->vT);
// mode 4: MERGED QKV+FF.
DEV void stage_half(const u16* __restrict__ gbase, int K, int kt, char* dst, int w, int l) {
#pragma unroll
  for (int j = 0; j < 2; ++j) {
    int s = w * 2 + j;
    int row = s * 8 + (l >> 3);
    int ksrc = ((l & 7) ^ (l >> 3)) << 3;
    const u16* src = gbase + (size_t)row * K + kt + ksrc;
    __builtin_amdgcn_global_load_lds(
        (const __attribute__((address_space(1))) unsigned int*)src,
        (__attribute__((address_space(3))) unsigned int*)(dst + s * 1024 + l * 16),
        16, 0, 0);
  }
}

DEV short8 ldfrag(const char* base, int row, int slot) {
  return *reinterpret_cast<const short8*>(base + row * 128 + (((slot ^ (row & 7)) << 4)));
}

__global__ __launch_bounds__(512) void gemm256(const u16* __restrict__ A,
                                               const u16* __restrict__ BT,
                                               const float* __restrict__ bias,
                                               void* __restrict__ Cout,
                                               u16* __restrict__ vTout,
                                               const float* __restrict__ sp,
                                               const float* __restrict__ cp,
                                               const u16* __restrict__ BT2,
                                               const float* __restrict__ bias2,
                                               void* __restrict__ Cout2,
                                               int K, int ldc, int mode, int NBX) {
  __shared__ float4 lds_v[9216];  // 147456 B
  char* lds = (char*)lds_v;
  int t = threadIdx.x;
  int w = t >> 6, l = t & 63, c = l & 15, g = l >> 4;
  int wr = w >> 1, wc = w & 1;

  // panel-pinning remap: all blocks of A-panel `by` share XCD by%8.
  int bid = blockIdx.x;
  int x8 = bid & 7, q = bid >> 3;
  int emode = mode, bx, by, ldcc = ldc;
  const u16* Bbase = BT;
  const float* biasp = bias;
  void* Cp = Cout;
  if (mode == 4) {  // merged QKV (q<96, NBX=24) + FF (q>=96, NBX=32)
    if (q < 96) {
      emode = 3; bx = q % 24; by = (q / 24) * 8 + x8; ldcc = 2048;
    } else {
      int q2 = q - 96;
      emode = 1; bx = q2 % 32; by = (q2 / 32) * 8 + x8; ldcc = 5120;
      Bbase = BT2; biasp = bias2; Cp = Cout2;
    }
  } else {
    bx = q % NBX;
    by = (q / NBX) * 8 + x8;
  }

  size_t m0 = (size_t)by * 256, n0 = (size_t)bx * 128;
  const u16* Ab = A + m0 * K;
  const u16* Bb = Bbase + n0 * K;
  int KT = K >> 6;

  f32x4 zero4 = {0.f, 0.f, 0.f, 0.f};
  f32x4 acc[4][4];
#pragma unroll
  for (int a = 0; a < 4; ++a)
#pragma unroll
    for (int b2 = 0; b2 < 4; ++b2) acc[a][b2] = zero4;

#pragma unroll
  for (int pt = 0; pt < 2; ++pt) {
    int boff = pt * 49152;
    stage_half(Ab, K, pt * 64, lds + boff, w, l);
    stage_half(Ab + (size_t)128 * K, K, pt * 64, lds + boff + 16384, w, l);
    stage_half(Bb, K, pt * 64, lds + boff + 32768, w, l);
  }
  VMW(6);
  __builtin_amdgcn_s_barrier();

  for (int tt = 0; tt < KT; ++tt) {
    const char* Abuf = lds + (tt % 3) * 49152;
    const char* Bbuf = Abuf + 32768;
    int b2off = ((tt + 2) % 3) * 49152;
    int kt2 = (tt + 2) * 64;
    bool pf = (tt + 2 < KT);

    if (pf) {
      stage_half(Ab, K, kt2, lds + b2off, w, l);
      stage_half(Ab + (size_t)128 * K, K, kt2, lds + b2off + 16384, w, l);
    }
    {
      short8 bv[4], av[4];
#pragma unroll
      for (int nj = 0; nj < 4; ++nj) bv[nj] = ldfrag(Bbuf, wc * 64 + 16 * nj + c, g);
#pragma unroll
      for (int mi = 0; mi < 4; ++mi) av[mi] = ldfrag(Abuf, wr * 64 + 16 * mi + c, g);
      __builtin_amdgcn_s_setprio(1);
#pragma unroll
      for (int mi = 0; mi < 4; ++mi)
#pragma unroll
        for (int nj = 0; nj < 4; ++nj)
          acc[mi][nj] = __builtin_amdgcn_mfma_f32_16x16x32_bf16(av[mi], bv[nj], acc[mi][nj], 0, 0, 0);
      __builtin_amdgcn_s_setprio(0);
    }
    __builtin_amdgcn_s_barrier();

    if (pf) stage_half(Bb, K, kt2, lds + b2off + 32768, w, l);
    {
      short8 bv[4], av[4];
#pragma unroll
      for (int nj = 0; nj < 4; ++nj) bv[nj] = ldfrag(Bbuf, wc * 64 + 16 * nj + c, 4 + g);
#pragma unroll
      for (int mi = 0; mi < 4; ++mi) av[mi] = ldfrag(Abuf, wr * 64 + 16 * mi + c, 4 + g);
      __builtin_amdgcn_s_setprio(1);
#pragma unroll
      for (int mi = 0; mi < 4; ++mi)
#pragma unroll
        for (int nj = 0; nj < 4; ++nj)
          acc[mi][nj] = __builtin_amdgcn_mfma_f32_16x16x32_bf16(av[mi], bv[nj], acc[mi][nj], 0, 0, 0);
      __builtin_amdgcn_s_setprio(0);
    }
    if (tt + 1 < KT) {
      if (pf)
        VMW(6);
      else
        VMW(0);
      __builtin_amdgcn_s_barrier();
    }
  }

  // ---- epilogue ----
  // per-wave LDS slice for column-gather: 2 alternating 16x68-f32 slabs.
  // LDS quiescent here (final boundary drained vmcnt to 0).
  float* swbase = (float*)lds + (size_t)w * 2176;
  int colb = (int)n0 + wc * 64 + 4 * c;  // 4 consecutive cols per lane

  if (emode == 3) {
    bool blockV = (n0 >= 2048);  // block-uniform: 2048 % 128 == 0
    if (!blockV) {
      // q/k: LDS gather -> bias -> rope in-lane -> u16x4 full-line store
      float scq = (colb < 1024) ? 0.125f : 1.0f;  // uniform per 64-col group
      float4 bb = *reinterpret_cast<const float4*>(biasp + colb);
      int d0 = colb & 63;  // = 4*c
#pragma unroll
      for (int mi = 0; mi < 4; ++mi) {
        float* sw = swbase + (mi & 1) * 1088;
        size_t rbase = m0 + wr * 64 + 16 * mi + 4 * g;
#pragma unroll
        for (int nj = 0; nj < 4; ++nj)
#pragma unroll
          for (int r = 0; r < 4; ++r)
            sw[(4 * g + r) * 68 + 16 * nj + c] = acc[mi][nj][r];
        asm volatile("s_waitcnt lgkmcnt(0)" ::: "memory");
#pragma unroll
        for (int r = 0; r < 4; ++r) {
          float4 f4 = *reinterpret_cast<const float4*>(&sw[(4 * g + r) * 68 + 4 * c]);
          float f0 = f4.x + bb.x, f1 = f4.y + bb.y, f2 = f4.z + bb.z, f3 = f4.w + bb.w;
          int pos = (int)((rbase + r) & 4095);
          float4 sv = *reinterpret_cast<const float4*>(sp + pos * 64 + d0);
          float4 cv = *reinterpret_cast<const float4*>(cp + pos * 64 + d0);
          u16x4 o;
          o[0] = f2bf((f0 * cv.x - f1 * sv.x) * scq);
          o[1] = f2bf((f1 * cv.y + f0 * sv.y) * scq);
          o[2] = f2bf((f2 * cv.z - f3 * sv.z) * scq);
          o[3] = f2bf((f3 * cv.w + f2 * sv.w) * scq);
          *reinterpret_cast<u16x4*>((u16*)Cp + (rbase + r) * (size_t)ldcc + colb) = o;
        }
      }
    } else {
      int b16 = ((int)(m0 >> 12)) * 16;
#pragma unroll
      for (int nj = 0; nj < 4; ++nj) {
        int col = (int)n0 + wc * 64 + 16 * nj + c;
        float bvv = biasp[col];
        int cv2 = col - 2048;
        int h = cv2 >> 6, d = cv2 & 63;
        u16* vb = vTout + ((size_t)(b16 + h)) * 262144 + (size_t)d * 4096;
#pragma unroll
        for (int mi = 0; mi < 4; ++mi) {
          size_t rbase = m0 + wr * 64 + 16 * mi + 4 * g;
          int s0 = (int)(rbase & 4095);
          u16x4 pk;
#pragma unroll
          for (int r = 0; r < 4; ++r) pk[r] = f2bf(acc[mi][nj][r] + bvv);
          *reinterpret_cast<u16x4*>(vb + s0) = pk;
        }
      }
    }
    return;
  }

  if (emode == 1) {
    // FF: LDS gather -> bias -> gelu -> u16x4 full-line store
    float4 bb = *reinterpret_cast<const float4*>(biasp + colb);
#pragma unroll
    for (int mi = 0; mi < 4; ++mi) {
      float* sw = swbase + (mi & 1) * 1088;
      size_t rbase = m0 + wr * 64 + 16 * mi + 4 * g;
#pragma unroll
      for (int nj = 0; nj < 4; ++nj)
#pragma unroll
        for (int r = 0; r < 4; ++r)
          sw[(4 * g + r) * 68 + 16 * nj + c] = acc[mi][nj][r];
      asm volatile("s_waitcnt lgkmcnt(0)" ::: "memory");
#pragma unroll
      for (int r = 0; r < 4; ++r) {
        float4 f4 = *reinterpret_cast<const float4*>(&sw[(4 * g + r) * 68 + 4 * c]);
        u16x4 o;
        o[0] = f2bf(fast_gelu(f4.x + bb.x));
        o[1] = f2bf(fast_gelu(f4.y + bb.y));
        o[2] = f2bf(fast_gelu(f4.z + bb.z));
        o[3] = f2bf(fast_gelu(f4.w + bb.w));
        *reinterpret_cast<u16x4*>((u16*)Cp + (rbase + r) * (size_t)ldcc + colb) = o;
      }
    }
    return;
  }

  // emode 2 (OUT, f32): 16 lanes x 4B already cover full 64B lines
#pragma unroll
  for (int nj = 0; nj < 4; ++nj) {
    int col = (int)n0 + wc * 64 + 16 * nj + c;
    float bvv = biasp[col];
#pragma unroll
    for (int mi = 0; mi < 4; ++mi) {
      size_t rbase = m0 + wr * 64 + 16 * mi + 4 * g;
#pragma unroll
      for (int r = 0; r < 4; ++r) {
        float f = acc[mi][nj][r] + bvv;
        ((float*)Cp)[(rbase + r) * (size_t)ldcc + col] = f;
      }
    }
  }
}

// ------------- sliding-window causal attention (R22 exact) ------------------
// 1 wave per 32-query tile, no barriers. grid = 4096, block = 64.
// qk rows: [q(1024)|k(1024)], stride 2048, pre-roped, q pre-scaled 0.125.
// K[t+1] and V[t] issued early, consumed late (T14). Defer-max (T13).
__global__ __launch_bounds__(64) void attn_kernel(const u16* __restrict__ qk,
                                                  const u16* __restrict__ vT,
                                                  u16* __restrict__ comb) {
  int bid = blockIdx.x;
  int swz = ((bid & 7) << 9) + (bid >> 3);  // 4096/8 = 512 per XCD
  int qt = swz & 127, h = (swz >> 7) & 15, b = swz >> 11;
  int l = threadIdx.x, c = l & 15, g = l >> 4;
  int q0 = qt * 32;
  const u16* qb = qk + (size_t)b * 4096 * 2048 + h * 64;
  const u16* kb = qb + 1024;
  const u16* vt = vT + (size_t)(b * 16 + h) * 64 * 4096;
  __shared__ u16 Pl[32 * 72];

  short8 qf[2][2];
#pragma unroll
  for (int mi = 0; mi < 2; ++mi)
#pragma unroll
    for (int kk = 0; kk < 2; ++kk)
      qf[mi][kk] = *reinterpret_cast<const short8*>(
          qb + (size_t)(q0 + 16 * mi + c) * 2048 + 32 * kk + 8 * g);

  f32x4 zero4 = {0.f, 0.f, 0.f, 0.f};
  f32x4 o[2][4];
  float mr[2][4], lr[2][4];
#pragma unroll
  for (int a = 0; a < 2; ++a)
#pragma unroll
    for (int d2 = 0; d2 < 4; ++d2) {
      o[a][d2] = zero4;
      mr[a][d2] = -1e30f;
      lr[a][d2] = 0.f;
    }

  int t_lo = (q0 >= 480) ? ((q0 - 480) >> 6) : 0;
  int t_hi = (q0 + 31) >> 6;

  short8 kfc[2][4], kfn[2][4], bv[2][4];
#pragma unroll
  for (int kk = 0; kk < 2; ++kk)
#pragma unroll
    for (int nj = 0; nj < 4; ++nj)
      kfc[kk][nj] = *reinterpret_cast<const short8*>(
          kb + (size_t)(t_lo * 64 + 16 * nj + c) * 2048 + 32 * kk + 8 * g);

  for (int tt = t_lo; tt <= t_hi; ++tt) {
    int kt0 = tt * 64;

    // issue V[t] loads (consumed at PV, after softmax)
#pragma unroll
    for (int kk = 0; kk < 2; ++kk)
#pragma unroll
      for (int dj = 0; dj < 4; ++dj)
        bv[kk][dj] = *reinterpret_cast<const short8*>(
            vt + (size_t)(16 * dj + c) * 4096 + kt0 + 32 * kk + 8 * g);

    // issue K[t+1] loads (consumed at the rotate, after PV)
    if (tt < t_hi) {
#pragma unroll
      for (int kk = 0; kk < 2; ++kk)
#pragma unroll
        for (int nj = 0; nj < 4; ++nj)
          kfn[kk][nj] = *reinterpret_cast<const short8*>(
              kb + (size_t)(kt0 + 64 + 16 * nj + c) * 2048 + 32 * kk + 8 * g);
    }

    // QK^T with current (pre-loaded) K frags
    f32x4 s[2][4];
#pragma unroll
    for (int a = 0; a < 2; ++a)
#pragma unroll
      for (int d2 = 0; d2 < 4; ++d2) s[a][d2] = zero4;
#pragma unroll
    for (int kk = 0; kk < 2; ++kk)
#pragma unroll
      for (int mi = 0; mi < 2; ++mi)
#pragma unroll
        for (int nj = 0; nj < 4; ++nj)
          s[mi][nj] = __builtin_amdgcn_mfma_f32_16x16x32_bf16(qf[mi][kk], kfc[kk][nj], s[mi][nj], 0, 0, 0);

    // mask only on the boundary tiles (wave-uniform branch)
    bool mc = (tt == t_hi), mw = (tt == t_lo);
    if (mc | mw) {
#pragma unroll
      for (int mi = 0; mi < 2; ++mi)
#pragma unroll
        for (int nj = 0; nj < 4; ++nj)
#pragma unroll
          for (int r = 0; r < 4; ++r) {
            int qg = q0 + 16 * mi + 4 * g + r;
            int kg = kt0 + 16 * nj + c;
            if ((mc && kg > qg) || (mw && qg - kg >= 512)) s[mi][nj][r] = -1e30f;
          }
    }

    // tile maxima + defer-max decision (wave-uniform)
    float tmv[2][4];
    float dmax = -1e30f;
#pragma unroll
    for (int mi = 0; mi < 2; ++mi)
#pragma unroll
      for (int r = 0; r < 4; ++r) {
        float tm = fmaxf(fmaxf(s[mi][0][r], s[mi][1][r]), fmaxf(s[mi][2][r], s[mi][3][r]));
        tm = redmax16(tm);
        tmv[mi][r] = tm;
        dmax = fmaxf(dmax, tm - mr[mi][r]);
      }
    if (!__all(dmax <= 8.0f)) {
#pragma unroll
      for (int mi = 0; mi < 2; ++mi)
#pragma unroll
        for (int r = 0; r < 4; ++r) {
          float mn = fmaxf(mr[mi][r], tmv[mi][r]);
          float a = __expf(mr[mi][r] - mn);
          mr[mi][r] = mn;
          lr[mi][r] *= a;
#pragma unroll
          for (int dj = 0; dj < 4; ++dj) o[mi][dj][r] *= a;
        }
    }

#pragma unroll
    for (int mi = 0; mi < 2; ++mi)
#pragma unroll
      for (int r = 0; r < 4; ++r) {
        float rs = 0.f;
        u16* pp = &Pl[(16 * mi + 4 * g + r) * 72 + c];
#pragma unroll
        for (int nj = 0; nj < 4; ++nj) {
          float p = __expf(s[mi][nj][r] - mr[mi][r]);
          rs += p;
          pp[16 * nj] = f2bf(p);  // natural k order, imm-offset ds_write_b16
        }
        rs = redsum16(rs);
        lr[mi][r] += rs;
      }

    // PV: A-frag from Pl, B-frag = V regs issued before softmax
#pragma unroll
    for (int kk = 0; kk < 2; ++kk) {
      short8 pa[2];
#pragma unroll
      for (int mi = 0; mi < 2; ++mi)
        pa[mi] = *reinterpret_cast<const short8*>(&Pl[(16 * mi + c) * 72 + 32 * kk + 8 * g]);
#pragma unroll
      for (int mi = 0; mi < 2; ++mi)
#pragma unroll
        for (int dj = 0; dj < 4; ++dj)
          o[mi][dj] = __builtin_amdgcn_mfma_f32_16x16x32_bf16(pa[mi], bv[kk][dj], o[mi][dj], 0, 0, 0);
    }

    // rotate: consume K[t+1] loads (they were in flight the whole tile)
    if (tt < t_hi) {
#pragma unroll
      for (int kk = 0; kk < 2; ++kk)
#pragma unroll
        for (int nj = 0; nj < 4; ++nj) kfc[kk][nj] = kfn[kk][nj];
    }
  }

  u16* ob = comb + (size_t)(b * 4096 + q0) * 5120 + h * 64;
#pragma unroll
  for (int mi = 0; mi < 2; ++mi)
#pragma unroll
    for (int r = 0; r < 4; ++r) {
      float inv = __builtin_amdgcn_rcpf(lr[mi][r]);
#pragma unroll
      for (int dj = 0; dj < 4; ++dj)
        ob[(size_t)(16 * mi + 4 * g + r) * 5120 + 16 * dj + c] = f2bf(o[mi][dj][r] * inv);
    }
}

// ---------------- launch ----------------
extern "C" void kernel_launch(void* const* d_in, const int* in_sizes, int n_in,
                              void* d_out, int out_size, void* d_ws, size_t ws_size,
                              hipStream_t stream) {
  const float* x = (const float*)d_in[0];
  const float* sinp = (const float*)d_in[1];
  const float* cosp = (const float*)d_in[2];
  const float* norm_w = (const float*)d_in[3];
  const float* w_qkv = (const float*)d_in[4];
  const float* b_qkv = (const float*)d_in[5];
  const float* w_in = (const float*)d_in[6];
  const float* b_in = (const float*)d_in[7];
  const float* w_out = (const float*)d_in[8];
  const float* b_out = (const float*)d_in[9];
  float* out = (float*)d_out;

  char* ws = (char*)d_ws;
  u16* xn = (u16*)(ws);                        // 8192*1024*2      = 16,777,216
  u16* qk = (u16*)(ws + 16777216);             // 8192*2048*2      = 33,554,432
  u16* vT = (u16*)(ws + 50331648);             // 32*64*4096*2     = 16,777,216
  u16* comb = (u16*)(ws + 67108864);           // 8192*5120*2      = 83,886,080
  u16* wqkvT = (u16*)(ws + 150994944);         // 3072*1024*2      = 6,291,456
  u16* winT = (u16*)(ws + 157286400);          // 4096*1024*2      = 8,388,608
  u16* woutT = (u16*)(ws + 165675008);         // 1024*5120*2      = 10,485,760

  // merged prep: 3 weight transposes + RMSNorm in one dispatch
  prep_all<<<20480, 256, 0, stream>>>(w_qkv, w_in, w_out, wqkvT, winT, woutT,
                                      x, norm_w, xn);

  // MERGED QKV + FF (mode 4): q<96 -> QKV (rope+scale -> qk; V -> vT),
  // q>=96 -> FF (gelu -> comb cols [1024,5120)). Both K=1024, same A (xn).
  gemm256<<<1792, 512, 0, stream>>>(
      xn, wqkvT, b_qkv, qk, vT, sinp, cosp, winT, b_in, comb + 1024,
      1024, 0, 4, 0);

  attn_kernel<<<4096, 64, 0, stream>>>(qk, vT, comb);

  // out = comb @ w_out + b_out  (f32 out)
  gemm256<<<256, 512, 0, stream>>>(
      comb, woutT, b_out, out, nullptr, nullptr, nullptr, nullptr, nullptr, nullptr,
      5120, 1024, 2, 8);
}